// Round 5
// baseline (366.581 us; speedup 1.0000x reference)
//
#include <hip/hip_runtime.h>
#include <math.h>

#define NNODES 50000
#define EORIG  800000
#define ETOT   850000     // EORIG + NNODES self loops
#define NB_SCAN 196       // ceil(NNODES/256)

typedef __attribute__((ext_vector_type(8))) short bf8_t;   // 8 bf16 (bits in shorts)
typedef __attribute__((ext_vector_type(4))) float f4_t;

constexpr size_t align256(size_t x){ return (x + 255) & ~size_t(255); }
constexpr size_t OFF_OFFSETS = 0;                                           // (N+1) ints
constexpr size_t OFF_BSUMS   = OFF_OFFSETS + align256((NNODES+1)*4);
constexpr size_t OFF_CURSOR  = OFF_BSUMS   + align256(256*4);
constexpr size_t OFF_SRC     = OFF_CURSOR  + align256(NNODES*4);            // ETOT ints
constexpr size_t OFF_AS1     = OFF_SRC     + align256((size_t)ETOT*4);      // N*8 f32
constexpr size_t OFF_AD1     = OFF_AS1     + align256((size_t)NNODES*8*4);
constexpr size_t OFF_W1T     = OFF_AD1     + align256((size_t)NNODES*8*4);  // 256*256 bf16 (n-major)
constexpr size_t OFF_W2T     = OFF_W1T     + align256(256*256*2);           // 64*256 bf16 (n-major)
constexpr size_t OFF_H1F8    = OFF_W2T     + align256(64*256*2);            // N*256 fp8
constexpr size_t OFF_OUT1B   = OFF_H1F8    + align256((size_t)NNODES*256);  // N*256 bf16
// h2b overlays dead h1f8 after aggregate1
constexpr size_t OFF_H2B     = OFF_H1F8;                                    // N*64 bf16 (6.4MB < 12.8MB)
constexpr size_t OFF_AS2     = OFF_OUT1B   + align256((size_t)NNODES*256*2);
constexpr size_t OFF_AD2     = OFF_AS2     + align256((size_t)NNODES*4);

__device__ __forceinline__ unsigned short f2bf(float f){
    union { float f; unsigned u; } v; v.f = f;
    unsigned r = v.u + 0x7FFF + ((v.u >> 16) & 1);   // RNE
    return (unsigned short)(r >> 16);
}
__device__ __forceinline__ float bf2f(unsigned short s){
    union { unsigned u; float f; } v; v.u = ((unsigned)s) << 16;
    return v.f;
}
// f32 -> fp8 e4m3fn: RNE, clamp to 448, FTZ below 2^-6 (no subnormals emitted)
__device__ __forceinline__ unsigned char f2fp8(float f){
    union { float f; unsigned u; } v; v.f = f;
    unsigned s = (v.u >> 24) & 0x80u;
    unsigned mag = v.u & 0x7fffffffu;
    if (mag > 0x43E00000u) mag = 0x43E00000u;        // clamp to 448
    if (mag < 0x3C800000u) return (unsigned char)s;  // FTZ -> +/-0
    unsigned r = mag + 0x7FFFFu + ((mag >> 20) & 1u);
    unsigned e = ((r >> 23) - 120u) & 0xFu;
    unsigned m = (r >> 20) & 7u;
    return (unsigned char)(s | (e << 3) | m);
}
// decode byte i of packed word (values never subnormal by construction)
__device__ __forceinline__ float fp8d(unsigned w, int i){
    unsigned b  = w >> (8*i);
    unsigned em = b & 0x7fu;
    union { unsigned u; float f; } v;
    v.u = ((b & 0x80u) << 24) | ((em << 20) + (120u << 23));
    return em ? v.f : 0.0f;
}

// ---------------- CSR construction ----------------

__global__ __launch_bounds__(256) void degree_k(const int* __restrict__ ei, int* __restrict__ cnt){
    int e = blockIdx.x*256 + threadIdx.x;
    if (e >= ETOT) return;
    int dst = (e < EORIG) ? ei[EORIG + e] : (e - EORIG);
    atomicAdd(&cnt[dst], 1);
}

__global__ __launch_bounds__(256) void scan_block_k(int* __restrict__ cnt, int* __restrict__ bsums){
    __shared__ int sm[256];
    int t = threadIdx.x;
    int idx = blockIdx.x*256 + t;
    int v = (idx < NNODES) ? cnt[idx] : 0;
    sm[t] = v; __syncthreads();
    for (int off = 1; off < 256; off <<= 1){
        int add = (t >= off) ? sm[t-off] : 0;
        __syncthreads();
        sm[t] += add;
        __syncthreads();
    }
    if (idx < NNODES) cnt[idx] = sm[t] - v;
    if (t == 255) bsums[blockIdx.x] = sm[t];
}

__global__ __launch_bounds__(256) void scan_top_k(int* __restrict__ bsums){
    __shared__ int sm[256];
    int t = threadIdx.x;
    int v = (t < NB_SCAN) ? bsums[t] : 0;
    sm[t] = v; __syncthreads();
    for (int off = 1; off < 256; off <<= 1){
        int add = (t >= off) ? sm[t-off] : 0;
        __syncthreads();
        sm[t] += add;
        __syncthreads();
    }
    if (t < NB_SCAN) bsums[t] = sm[t] - v;
}

__global__ __launch_bounds__(256) void scan_add_k(int* __restrict__ offs, const int* __restrict__ bsums,
                                                  int* __restrict__ cursor){
    int idx = blockIdx.x*256 + threadIdx.x;
    if (idx < NNODES){
        int o = offs[idx] + bsums[blockIdx.x];
        offs[idx] = o;
        cursor[idx] = o;
    }
    if (blockIdx.x == 0 && threadIdx.x == 0) offs[NNODES] = ETOT;
}

__global__ __launch_bounds__(256) void scatter_k(const int* __restrict__ ei, int* __restrict__ cursor,
                                                 int* __restrict__ srclist){
    int e = blockIdx.x*256 + threadIdx.x;
    if (e >= ETOT) return;
    int src, dst;
    if (e < EORIG){ src = ei[e]; dst = ei[EORIG + e]; }
    else          { src = dst = e - EORIG; }
    int pos = atomicAdd(&cursor[dst], 1);
    srclist[pos] = src;
}

// ---------------- weight transpose+convert (both layers, one launch) -------

__global__ __launch_bounds__(256) void conv_w_k(const float* __restrict__ W1, const float* __restrict__ W2,
                                                short* __restrict__ w1t, short* __restrict__ w2t){
    int o = blockIdx.x*256 + threadIdx.x;
    if (o < 256*256){
        int n = o >> 8, k = o & 255;
        w1t[o] = (short)f2bf(W1[k*256 + n]);
    } else {
        int o2 = o - 256*256;
        if (o2 < 64*256){
            int n = o2 >> 8, k = o2 & 255;
            w2t[o2] = (short)f2bf(W2[k*64 + n]);
        }
    }
}

// ---------------- GEMM1 (MFMA): h1f8 = fp8(x @ W1), fused f32->bf16 A-stage
// + fused as1/ad1 epilogue.  128x256 tile (full width -> x read once),
// 512 threads = 2x4 waves of 64x64, BK=32.

__global__ __launch_bounds__(512) void gemm1_mfma(const float* __restrict__ x, const short* __restrict__ w1t,
        const float* __restrict__ a1s, const float* __restrict__ a1d,
        unsigned char* __restrict__ h1f8, float* __restrict__ as1, float* __restrict__ ad1){
    __shared__ short As[128][40];   // +8 pad: 16B-aligned frags, 2-way banks = free
    __shared__ short Bs[256][40];   // Bs[n][k] (from pre-transposed W1T)
    const int t = threadIdx.x;                 // 0..511
    const int lane = t & 63, wave = t >> 6;    // 8 waves
    const int wy = wave >> 2, wx = wave & 3;   // 2 x 4 wave grid
    const int quad = lane >> 4, l15 = lane & 15;
    const int r0 = blockIdx.x * 128;
    const int srow = t >> 2, skoff = (t & 3) * 8;   // srow 0..127
    f4_t zero4 = {0.f,0.f,0.f,0.f};
    f4_t acc[4][4];
#pragma unroll
    for (int i=0;i<4;i++)
#pragma unroll
      for (int j=0;j<4;j++) acc[i][j] = zero4;

    for (int kk = 0; kk < 256; kk += 32){
        float4 xa0 = {0,0,0,0}, xa1 = {0,0,0,0};
        if (r0 + srow < NNODES){
            xa0 = *(const float4*)(x + (size_t)(r0+srow)*256 + kk + skoff);
            xa1 = *(const float4*)(x + (size_t)(r0+srow)*256 + kk + skoff + 4);
        }
        bf8_t b0  = *(const bf8_t*)(w1t + (size_t)(srow      )*256 + kk + skoff);
        bf8_t b1v = *(const bf8_t*)(w1t + (size_t)(srow + 128)*256 + kk + skoff);
        bf8_t a0;
        a0[0]=f2bf(xa0.x); a0[1]=f2bf(xa0.y); a0[2]=f2bf(xa0.z); a0[3]=f2bf(xa0.w);
        a0[4]=f2bf(xa1.x); a0[5]=f2bf(xa1.y); a0[6]=f2bf(xa1.z); a0[7]=f2bf(xa1.w);
        __syncthreads();
        *(bf8_t*)&As[srow     ][skoff] = a0;
        *(bf8_t*)&Bs[srow     ][skoff] = b0;
        *(bf8_t*)&Bs[srow+128][skoff] = b1v;
        __syncthreads();
        bf8_t af[4], bfr[4];
#pragma unroll
        for (int i=0;i<4;i++) af[i]  = *(const bf8_t*)&As[wy*64 + i*16 + l15][quad*8];
#pragma unroll
        for (int j=0;j<4;j++) bfr[j] = *(const bf8_t*)&Bs[wx*64 + j*16 + l15][quad*8];
#pragma unroll
        for (int i=0;i<4;i++)
#pragma unroll
          for (int j=0;j<4;j++)
            acc[i][j] = __builtin_amdgcn_mfma_f32_16x16x32_bf16(af[i], bfr[j], acc[i][j], 0,0,0);
    }
    // epilogue: fp8 store + fused alpha projections
    const int colbase = wx*64;               // this wave's 64 cols = 2 heads
    const int head0 = colbase >> 5;
    float cs[4], cd[4];
#pragma unroll
    for (int j=0;j<4;j++){ cs[j] = a1s[colbase + j*16 + l15]; cd[j] = a1d[colbase + j*16 + l15]; }
#pragma unroll
    for (int i=0;i<4;i++){
        int rowb = r0 + wy*64 + i*16 + quad*4;
#pragma unroll
        for (int reg=0; reg<4; reg++){
            int row = rowb + reg;
            bool valid = row < NNODES;
            float sp0=0.f, dp0=0.f, sp1=0.f, dp1=0.f;
#pragma unroll
            for (int j=0;j<4;j++){
                float v = acc[i][j][reg];
                if (j < 2){ sp0 += v*cs[j]; dp0 += v*cd[j]; }
                else      { sp1 += v*cs[j]; dp1 += v*cd[j]; }
                if (valid) h1f8[(size_t)row*256 + colbase + j*16 + l15] = f2fp8(v);
            }
            sp0 += __shfl_xor(sp0,1); sp0 += __shfl_xor(sp0,2); sp0 += __shfl_xor(sp0,4); sp0 += __shfl_xor(sp0,8);
            dp0 += __shfl_xor(dp0,1); dp0 += __shfl_xor(dp0,2); dp0 += __shfl_xor(dp0,4); dp0 += __shfl_xor(dp0,8);
            sp1 += __shfl_xor(sp1,1); sp1 += __shfl_xor(sp1,2); sp1 += __shfl_xor(sp1,4); sp1 += __shfl_xor(sp1,8);
            dp1 += __shfl_xor(dp1,1); dp1 += __shfl_xor(dp1,2); dp1 += __shfl_xor(dp1,4); dp1 += __shfl_xor(dp1,8);
            if (valid && l15 == 0){
                as1[row*8 + head0    ] = sp0;
                ad1[row*8 + head0    ] = dp0;
                as1[row*8 + head0 + 1] = sp1;
                ad1[row*8 + head0 + 1] = dp1;
            }
        }
    }
}

// ---------------- GEMM2 (MFMA): h2b = bf16(out1b @ W2), fused as2/ad2 ------
// 128x64 tile, BK=32, 4 waves stacked over rows (each 32 rows x 64 cols).

__global__ __launch_bounds__(256) void gemm2_mfma(const short* __restrict__ ab, const short* __restrict__ w2t,
        const float* __restrict__ a2s, const float* __restrict__ a2d,
        short* __restrict__ h2b, float* __restrict__ as2, float* __restrict__ ad2){
    __shared__ short As[128][40];
    __shared__ short Bs[64][40];
    const int t = threadIdx.x;
    const int lane = t & 63, wave = t >> 6;
    const int quad = lane >> 4, l15 = lane & 15;
    const int r0 = blockIdx.x * 128;
    const int srow = t >> 2, skoff = (t & 3) * 8;
    f4_t zero4 = {0.f,0.f,0.f,0.f};
    f4_t acc[2][4];
#pragma unroll
    for (int i=0;i<2;i++)
#pragma unroll
      for (int j=0;j<4;j++) acc[i][j] = zero4;

    for (int kk = 0; kk < 256; kk += 32){
        bf8_t a0 = {}, a1v = {};
        if (r0 + srow < NNODES)      a0  = *(const bf8_t*)(ab + (size_t)(r0+srow)*256 + kk + skoff);
        if (r0 + srow + 64 < NNODES) a1v = *(const bf8_t*)(ab + (size_t)(r0+srow+64)*256 + kk + skoff);
        bf8_t b0 = *(const bf8_t*)(w2t + (size_t)srow*256 + kk + skoff);   // srow = n (0..63)
        __syncthreads();
        *(bf8_t*)&As[srow   ][skoff] = a0;
        *(bf8_t*)&As[srow+64][skoff] = a1v;
        *(bf8_t*)&Bs[srow   ][skoff] = b0;
        __syncthreads();
        bf8_t af[2], bfr[4];
#pragma unroll
        for (int i=0;i<2;i++) af[i]  = *(const bf8_t*)&As[wave*32 + i*16 + l15][quad*8];
#pragma unroll
        for (int j=0;j<4;j++) bfr[j] = *(const bf8_t*)&Bs[j*16 + l15][quad*8];
#pragma unroll
        for (int i=0;i<2;i++)
#pragma unroll
          for (int j=0;j<4;j++)
            acc[i][j] = __builtin_amdgcn_mfma_f32_16x16x32_bf16(af[i], bfr[j], acc[i][j], 0,0,0);
    }
    float cs[4], cd[4];
#pragma unroll
    for (int j=0;j<4;j++){ cs[j] = a2s[j*16 + l15]; cd[j] = a2d[j*16 + l15]; }
#pragma unroll
    for (int i=0;i<2;i++){
        int rowb = r0 + wave*32 + i*16 + quad*4;
#pragma unroll
        for (int reg=0; reg<4; reg++){
            int row = rowb + reg;
            bool valid = row < NNODES;
            float sp=0.f, dp=0.f;
#pragma unroll
            for (int j=0;j<4;j++){
                float v = acc[i][j][reg];
                sp += v*cs[j]; dp += v*cd[j];
                if (valid) h2b[(size_t)row*64 + j*16 + l15] = (short)f2bf(v);
            }
            sp += __shfl_xor(sp,1); sp += __shfl_xor(sp,2); sp += __shfl_xor(sp,4); sp += __shfl_xor(sp,8);
            dp += __shfl_xor(dp,1); dp += __shfl_xor(dp,2); dp += __shfl_xor(dp,4); dp += __shfl_xor(dp,8);
            if (valid && l15 == 0){ as2[row] = sp; ad2[row] = dp; }
        }
    }
}

// ---------------- attention aggregation (single-pass, unroll-4) ------------
// Layer 1 gathers fp8 h1; attention weights stay fp32.

__global__ __launch_bounds__(256) void aggregate1_k(const unsigned char* __restrict__ h1f8,
        const float* __restrict__ as1, const float* __restrict__ ad1,
        const int* __restrict__ offsets, const int* __restrict__ srclist,
        const float* __restrict__ b1, short* __restrict__ out1b){
    int d = blockIdx.x*4 + (threadIdx.x >> 6);
    int lane = threadIdx.x & 63;
    if (d >= NNODES) return;
    int hh = lane >> 3;
    int start = offsets[d], end = offsets[d+1];
    float ad_h = ad1[d*8 + hh];
    float denom = 0.f;
    float4 acc = make_float4(0.f,0.f,0.f,0.f);
    int k = start;
    for (; k + 3 < end; k += 4){
        int s0 = srclist[k], s1 = srclist[k+1], s2 = srclist[k+2], s3 = srclist[k+3];
        float e0 = as1[s0*8 + hh] + ad_h;
        float e1 = as1[s1*8 + hh] + ad_h;
        float e2 = as1[s2*8 + hh] + ad_h;
        float e3 = as1[s3*8 + hh] + ad_h;
        unsigned w0 = *(const unsigned*)(h1f8 + (size_t)s0*256 + lane*4);
        unsigned w1 = *(const unsigned*)(h1f8 + (size_t)s1*256 + lane*4);
        unsigned w2 = *(const unsigned*)(h1f8 + (size_t)s2*256 + lane*4);
        unsigned w3 = *(const unsigned*)(h1f8 + (size_t)s3*256 + lane*4);
        e0 = (e0 > 0.f) ? e0 : 0.2f*e0;
        e1 = (e1 > 0.f) ? e1 : 0.2f*e1;
        e2 = (e2 > 0.f) ? e2 : 0.2f*e2;
        e3 = (e3 > 0.f) ? e3 : 0.2f*e3;
        float p0 = __expf(e0), p1 = __expf(e1), p2 = __expf(e2), p3 = __expf(e3);
        denom += (p0 + p1) + (p2 + p3);
        acc.x += p0*fp8d(w0,0) + p1*fp8d(w1,0) + p2*fp8d(w2,0) + p3*fp8d(w3,0);
        acc.y += p0*fp8d(w0,1) + p1*fp8d(w1,1) + p2*fp8d(w2,1) + p3*fp8d(w3,1);
        acc.z += p0*fp8d(w0,2) + p1*fp8d(w1,2) + p2*fp8d(w2,2) + p3*fp8d(w3,2);
        acc.w += p0*fp8d(w0,3) + p1*fp8d(w1,3) + p2*fp8d(w2,3) + p3*fp8d(w3,3);
    }
    for (; k < end; k++){
        int s0 = srclist[k];
        float e0 = as1[s0*8 + hh] + ad_h;
        unsigned w0 = *(const unsigned*)(h1f8 + (size_t)s0*256 + lane*4);
        e0 = (e0 > 0.f) ? e0 : 0.2f*e0;
        float p0 = __expf(e0);
        denom += p0;
        acc.x += p0*fp8d(w0,0); acc.y += p0*fp8d(w0,1);
        acc.z += p0*fp8d(w0,2); acc.w += p0*fp8d(w0,3);
    }
    float inv = 1.f / denom;
    float4 bv = *(const float4*)(b1 + lane*4);
    ushort4 us;
    us.x = f2bf(fmaxf(acc.x*inv + bv.x, 0.f));
    us.y = f2bf(fmaxf(acc.y*inv + bv.y, 0.f));
    us.z = f2bf(fmaxf(acc.z*inv + bv.z, 0.f));
    us.w = f2bf(fmaxf(acc.w*inv + bv.w, 0.f));
    *(ushort4*)(out1b + (size_t)d*256 + lane*4) = us;
}

__global__ __launch_bounds__(256) void aggregate2_k(const unsigned short* __restrict__ h2b,
        const float* __restrict__ as2, const float* __restrict__ ad2,
        const int* __restrict__ offsets, const int* __restrict__ srclist,
        const float* __restrict__ b2, float* __restrict__ out){
    int d = blockIdx.x*4 + (threadIdx.x >> 6);
    int lane = threadIdx.x & 63;
    if (d >= NNODES) return;
    int start = offsets[d], end = offsets[d+1];
    float ad_v = ad2[d];
    float denom = 0.f, acc = 0.f;
    int k = start;
    for (; k + 3 < end; k += 4){
        int s0 = srclist[k], s1 = srclist[k+1], s2 = srclist[k+2], s3 = srclist[k+3];
        float e0 = as2[s0] + ad_v;
        float e1 = as2[s1] + ad_v;
        float e2 = as2[s2] + ad_v;
        float e3 = as2[s3] + ad_v;
        unsigned short u0 = h2b[(size_t)s0*64 + lane];
        unsigned short u1 = h2b[(size_t)s1*64 + lane];
        unsigned short u2 = h2b[(size_t)s2*64 + lane];
        unsigned short u3 = h2b[(size_t)s3*64 + lane];
        e0 = (e0 > 0.f) ? e0 : 0.2f*e0;
        e1 = (e1 > 0.f) ? e1 : 0.2f*e1;
        e2 = (e2 > 0.f) ? e2 : 0.2f*e2;
        e3 = (e3 > 0.f) ? e3 : 0.2f*e3;
        float p0 = __expf(e0), p1 = __expf(e1), p2 = __expf(e2), p3 = __expf(e3);
        denom += (p0 + p1) + (p2 + p3);
        acc += p0*bf2f(u0) + p1*bf2f(u1) + p2*bf2f(u2) + p3*bf2f(u3);
    }
    for (; k < end; k++){
        int s0 = srclist[k];
        float e0 = as2[s0] + ad_v;
        unsigned short u0 = h2b[(size_t)s0*64 + lane];
        e0 = (e0 > 0.f) ? e0 : 0.2f*e0;
        float p0 = __expf(e0);
        denom += p0;
        acc += p0*bf2f(u0);
    }
    float v = acc/denom + b2[lane];
    float mx = v;
#pragma unroll
    for (int off = 1; off < 64; off <<= 1) mx = fmaxf(mx, __shfl_xor(mx, off));
    float ex = __expf(v - mx);
    float ss = ex;
#pragma unroll
    for (int off = 1; off < 64; off <<= 1) ss += __shfl_xor(ss, off);
    out[(size_t)d*64 + lane] = v - mx - logf(ss);
}

// ---------------- launch ----------------

extern "C" void kernel_launch(void* const* d_in, const int* in_sizes, int n_in,
                              void* d_out, int out_size, void* d_ws, size_t ws_size,
                              hipStream_t stream){
    const float* x      = (const float*)d_in[0];
    const int*   ei     = (const int*)  d_in[1];
    const float* W1     = (const float*)d_in[2];
    const float* a_src1 = (const float*)d_in[3];
    const float* a_dst1 = (const float*)d_in[4];
    const float* b1     = (const float*)d_in[5];
    const float* W2     = (const float*)d_in[6];
    const float* a_src2 = (const float*)d_in[7];
    const float* a_dst2 = (const float*)d_in[8];
    const float* b2     = (const float*)d_in[9];

    char* ws = (char*)d_ws;
    int*   offsets = (int*)  (ws + OFF_OFFSETS);
    int*   bsums   = (int*)  (ws + OFF_BSUMS);
    int*   cursor  = (int*)  (ws + OFF_CURSOR);
    int*   srclist = (int*)  (ws + OFF_SRC);
    float* as1     = (float*)(ws + OFF_AS1);
    float* ad1     = (float*)(ws + OFF_AD1);
    short* w1t     = (short*)(ws + OFF_W1T);
    short* w2t     = (short*)(ws + OFF_W2T);
    unsigned char* h1f8 = (unsigned char*)(ws + OFF_H1F8);
    short* out1b   = (short*)(ws + OFF_OUT1B);
    short* h2b     = (short*)(ws + OFF_H2B);
    float* as2     = (float*)(ws + OFF_AS2);
    float* ad2     = (float*)(ws + OFF_AD2);

    // CSR by dst
    hipMemsetAsync(offsets, 0, (NNODES+1)*sizeof(int), stream);
    degree_k    <<<(ETOT+255)/256, 256, 0, stream>>>(ei, offsets);
    scan_block_k<<<NB_SCAN, 256, 0, stream>>>(offsets, bsums);
    scan_top_k  <<<1, 256, 0, stream>>>(bsums);
    scan_add_k  <<<NB_SCAN, 256, 0, stream>>>(offsets, bsums, cursor);
    scatter_k   <<<(ETOT+255)/256, 256, 0, stream>>>(ei, cursor, srclist);

    // weight prep (one launch for both layers)
    conv_w_k<<<(256*256 + 64*256 + 255)/256, 256, 0, stream>>>(W1, W2, w1t, w2t);

    // Layer 1
    gemm1_mfma<<<(NNODES+127)/128, 512, 0, stream>>>(x, w1t, a_src1, a_dst1, h1f8, as1, ad1);
    aggregate1_k<<<(NNODES+3)/4, 256, 0, stream>>>(h1f8, as1, ad1, offsets, srclist, b1, out1b);

    // Layer 2
    gemm2_mfma<<<(NNODES+127)/128, 256, 0, stream>>>(out1b, w2t, a_src2, a_dst2, h2b, as2, ad2);
    aggregate2_k<<<(NNODES+3)/4, 256, 0, stream>>>((const unsigned short*)h2b, as2, ad2, offsets, srclist, b2, (float*)d_out);
}

// Round 6
// 329.175 us; speedup vs baseline: 1.1136x; 1.1136x over previous
//
#include <hip/hip_runtime.h>
#include <math.h>

#define NNODES 50000
#define EORIG  800000
#define ETOT   850000     // EORIG + NNODES self loops
#define NB_SCAN 196       // ceil(NNODES/256)

typedef __attribute__((ext_vector_type(8))) short bf8_t;   // 8 bf16 (bits in shorts)
typedef __attribute__((ext_vector_type(4))) float f4_t;
typedef __attribute__((ext_vector_type(2))) float f2_t;

constexpr size_t align256(size_t x){ return (x + 255) & ~size_t(255); }
constexpr size_t OFF_OFFSETS = 0;                                           // (N+1) ints
constexpr size_t OFF_BSUMS   = OFF_OFFSETS + align256((NNODES+1)*4);
constexpr size_t OFF_CURSOR  = OFF_BSUMS   + align256(256*4);
constexpr size_t OFF_SRC     = OFF_CURSOR  + align256(NNODES*4);            // ETOT ints
constexpr size_t OFF_AS1     = OFF_SRC     + align256((size_t)ETOT*4);      // N*8 f32
constexpr size_t OFF_AD1     = OFF_AS1     + align256((size_t)NNODES*8*4);
constexpr size_t OFF_W1T     = OFF_AD1     + align256((size_t)NNODES*8*4);  // 256*256 bf16 (n-major)
constexpr size_t OFF_W2T     = OFF_W1T     + align256(256*256*2);           // 64*256 bf16 (n-major)
constexpr size_t OFF_H1F8    = OFF_W2T     + align256(64*256*2);            // N*256 fp8
constexpr size_t OFF_OUT1B   = OFF_H1F8    + align256((size_t)NNODES*256);  // N*256 bf16
// h2b overlays dead h1f8 after aggregate1
constexpr size_t OFF_H2B     = OFF_H1F8;                                    // N*64 bf16 (6.4MB < 12.8MB)
constexpr size_t OFF_AS2     = OFF_OUT1B   + align256((size_t)NNODES*256*2);
constexpr size_t OFF_AD2     = OFF_AS2     + align256((size_t)NNODES*4);

__device__ __forceinline__ unsigned short f2bf(float f){
    union { float f; unsigned u; } v; v.f = f;
    unsigned r = v.u + 0x7FFF + ((v.u >> 16) & 1);   // RNE
    return (unsigned short)(r >> 16);
}
__device__ __forceinline__ float bf2f(unsigned short s){
    union { unsigned u; float f; } v; v.u = ((unsigned)s) << 16;
    return v.f;
}

// ---------------- CSR construction ----------------

__global__ __launch_bounds__(256) void degree_k(const int* __restrict__ ei, int* __restrict__ cnt){
    int e = blockIdx.x*256 + threadIdx.x;
    if (e >= ETOT) return;
    int dst = (e < EORIG) ? ei[EORIG + e] : (e - EORIG);
    atomicAdd(&cnt[dst], 1);
}

__global__ __launch_bounds__(256) void scan_block_k(int* __restrict__ cnt, int* __restrict__ bsums){
    __shared__ int sm[256];
    int t = threadIdx.x;
    int idx = blockIdx.x*256 + t;
    int v = (idx < NNODES) ? cnt[idx] : 0;
    sm[t] = v; __syncthreads();
    for (int off = 1; off < 256; off <<= 1){
        int add = (t >= off) ? sm[t-off] : 0;
        __syncthreads();
        sm[t] += add;
        __syncthreads();
    }
    if (idx < NNODES) cnt[idx] = sm[t] - v;
    if (t == 255) bsums[blockIdx.x] = sm[t];
}

__global__ __launch_bounds__(256) void scan_top_k(int* __restrict__ bsums){
    __shared__ int sm[256];
    int t = threadIdx.x;
    int v = (t < NB_SCAN) ? bsums[t] : 0;
    sm[t] = v; __syncthreads();
    for (int off = 1; off < 256; off <<= 1){
        int add = (t >= off) ? sm[t-off] : 0;
        __syncthreads();
        sm[t] += add;
        __syncthreads();
    }
    if (t < NB_SCAN) bsums[t] = sm[t] - v;
}

__global__ __launch_bounds__(256) void scan_add_k(int* __restrict__ offs, const int* __restrict__ bsums,
                                                  int* __restrict__ cursor){
    int idx = blockIdx.x*256 + threadIdx.x;
    if (idx < NNODES){
        int o = offs[idx] + bsums[blockIdx.x];
        offs[idx] = o;
        cursor[idx] = o;
    }
    if (blockIdx.x == 0 && threadIdx.x == 0) offs[NNODES] = ETOT;
}

__global__ __launch_bounds__(256) void scatter_k(const int* __restrict__ ei, int* __restrict__ cursor,
                                                 int* __restrict__ srclist){
    int e = blockIdx.x*256 + threadIdx.x;
    if (e >= ETOT) return;
    int src, dst;
    if (e < EORIG){ src = ei[e]; dst = ei[EORIG + e]; }
    else          { src = dst = e - EORIG; }
    int pos = atomicAdd(&cursor[dst], 1);
    srclist[pos] = src;
}

// ---------------- weight transpose+convert (both layers, one launch) -------

__global__ __launch_bounds__(256) void conv_w_k(const float* __restrict__ W1, const float* __restrict__ W2,
                                                short* __restrict__ w1t, short* __restrict__ w2t){
    int o = blockIdx.x*256 + threadIdx.x;
    if (o < 256*256){
        int n = o >> 8, k = o & 255;
        w1t[o] = (short)f2bf(W1[k*256 + n]);
    } else {
        int o2 = o - 256*256;
        if (o2 < 64*256){
            int n = o2 >> 8, k = o2 & 255;
            w2t[o2] = (short)f2bf(W2[k*64 + n]);
        }
    }
}

// ---------------- GEMM1 (MFMA): h1f8 = fp8(x @ W1), fused f32->bf16 A-stage
// + fused as1/ad1 epilogue.  128x256 tile (full width -> x read once),
// 512 threads = 2x4 waves of 64x64, BK=32.

__global__ __launch_bounds__(512) void gemm1_mfma(const float* __restrict__ x, const short* __restrict__ w1t,
        const float* __restrict__ a1s, const float* __restrict__ a1d,
        unsigned char* __restrict__ h1f8, float* __restrict__ as1, float* __restrict__ ad1){
    __shared__ short As[128][40];   // +8 pad: 16B-aligned frags, 2-way banks = free
    __shared__ short Bs[256][40];   // Bs[n][k] (from pre-transposed W1T)
    const int t = threadIdx.x;                 // 0..511
    const int lane = t & 63, wave = t >> 6;    // 8 waves
    const int wy = wave >> 2, wx = wave & 3;   // 2 x 4 wave grid
    const int quad = lane >> 4, l15 = lane & 15;
    const int r0 = blockIdx.x * 128;
    const int srow = t >> 2, skoff = (t & 3) * 8;   // srow 0..127
    f4_t zero4 = {0.f,0.f,0.f,0.f};
    f4_t acc[4][4];
#pragma unroll
    for (int i=0;i<4;i++)
#pragma unroll
      for (int j=0;j<4;j++) acc[i][j] = zero4;

    for (int kk = 0; kk < 256; kk += 32){
        float4 xa0 = {0,0,0,0}, xa1 = {0,0,0,0};
        if (r0 + srow < NNODES){
            xa0 = *(const float4*)(x + (size_t)(r0+srow)*256 + kk + skoff);
            xa1 = *(const float4*)(x + (size_t)(r0+srow)*256 + kk + skoff + 4);
        }
        bf8_t b0  = *(const bf8_t*)(w1t + (size_t)(srow      )*256 + kk + skoff);
        bf8_t b1v = *(const bf8_t*)(w1t + (size_t)(srow + 128)*256 + kk + skoff);
        bf8_t a0;
        a0[0]=f2bf(xa0.x); a0[1]=f2bf(xa0.y); a0[2]=f2bf(xa0.z); a0[3]=f2bf(xa0.w);
        a0[4]=f2bf(xa1.x); a0[5]=f2bf(xa1.y); a0[6]=f2bf(xa1.z); a0[7]=f2bf(xa1.w);
        __syncthreads();
        *(bf8_t*)&As[srow     ][skoff] = a0;
        *(bf8_t*)&Bs[srow     ][skoff] = b0;
        *(bf8_t*)&Bs[srow+128][skoff] = b1v;
        __syncthreads();
        bf8_t af[4], bfr[4];
#pragma unroll
        for (int i=0;i<4;i++) af[i]  = *(const bf8_t*)&As[wy*64 + i*16 + l15][quad*8];
#pragma unroll
        for (int j=0;j<4;j++) bfr[j] = *(const bf8_t*)&Bs[wx*64 + j*16 + l15][quad*8];
#pragma unroll
        for (int i=0;i<4;i++)
#pragma unroll
          for (int j=0;j<4;j++)
            acc[i][j] = __builtin_amdgcn_mfma_f32_16x16x32_bf16(af[i], bfr[j], acc[i][j], 0,0,0);
    }
    // epilogue: fp8 store (HW cvt, OCP e4m3fn) + fused alpha projections
    const int colbase = wx*64;               // this wave's 64 cols = 2 heads
    const int head0 = colbase >> 5;
    float cs[4], cd[4];
#pragma unroll
    for (int j=0;j<4;j++){ cs[j] = a1s[colbase + j*16 + l15]; cd[j] = a1d[colbase + j*16 + l15]; }
#pragma unroll
    for (int i=0;i<4;i++){
        int rowb = r0 + wy*64 + i*16 + quad*4;
#pragma unroll
        for (int reg=0; reg<4; reg++){
            int row = rowb + reg;
            bool valid = row < NNODES;
            float sp0=0.f, dp0=0.f, sp1=0.f, dp1=0.f;
#pragma unroll
            for (int j=0;j<4;j++){
                float v = acc[i][j][reg];
                if (j < 2){ sp0 += v*cs[j]; dp0 += v*cd[j]; }
                else      { sp1 += v*cs[j]; dp1 += v*cd[j]; }
                if (valid){
                    unsigned enc = (unsigned)__builtin_amdgcn_cvt_pk_fp8_f32(v, v, 0, false);
                    h1f8[(size_t)row*256 + colbase + j*16 + l15] = (unsigned char)(enc & 0xffu);
                }
            }
            sp0 += __shfl_xor(sp0,1); sp0 += __shfl_xor(sp0,2); sp0 += __shfl_xor(sp0,4); sp0 += __shfl_xor(sp0,8);
            dp0 += __shfl_xor(dp0,1); dp0 += __shfl_xor(dp0,2); dp0 += __shfl_xor(dp0,4); dp0 += __shfl_xor(dp0,8);
            sp1 += __shfl_xor(sp1,1); sp1 += __shfl_xor(sp1,2); sp1 += __shfl_xor(sp1,4); sp1 += __shfl_xor(sp1,8);
            dp1 += __shfl_xor(dp1,1); dp1 += __shfl_xor(dp1,2); dp1 += __shfl_xor(dp1,4); dp1 += __shfl_xor(dp1,8);
            if (valid && l15 == 0){
                as1[row*8 + head0    ] = sp0;
                ad1[row*8 + head0    ] = dp0;
                as1[row*8 + head0 + 1] = sp1;
                ad1[row*8 + head0 + 1] = dp1;
            }
        }
    }
}

// ---------------- GEMM2 (MFMA): h2b = bf16(out1b @ W2), fused as2/ad2 ------
// 128x64 tile, BK=32, 4 waves stacked over rows (each 32 rows x 64 cols).

__global__ __launch_bounds__(256) void gemm2_mfma(const short* __restrict__ ab, const short* __restrict__ w2t,
        const float* __restrict__ a2s, const float* __restrict__ a2d,
        short* __restrict__ h2b, float* __restrict__ as2, float* __restrict__ ad2){
    __shared__ short As[128][40];
    __shared__ short Bs[64][40];
    const int t = threadIdx.x;
    const int lane = t & 63, wave = t >> 6;
    const int quad = lane >> 4, l15 = lane & 15;
    const int r0 = blockIdx.x * 128;
    const int srow = t >> 2, skoff = (t & 3) * 8;
    f4_t zero4 = {0.f,0.f,0.f,0.f};
    f4_t acc[2][4];
#pragma unroll
    for (int i=0;i<2;i++)
#pragma unroll
      for (int j=0;j<4;j++) acc[i][j] = zero4;

    for (int kk = 0; kk < 256; kk += 32){
        bf8_t a0 = {}, a1v = {};
        if (r0 + srow < NNODES)      a0  = *(const bf8_t*)(ab + (size_t)(r0+srow)*256 + kk + skoff);
        if (r0 + srow + 64 < NNODES) a1v = *(const bf8_t*)(ab + (size_t)(r0+srow+64)*256 + kk + skoff);
        bf8_t b0 = *(const bf8_t*)(w2t + (size_t)srow*256 + kk + skoff);   // srow = n (0..63)
        __syncthreads();
        *(bf8_t*)&As[srow   ][skoff] = a0;
        *(bf8_t*)&As[srow+64][skoff] = a1v;
        *(bf8_t*)&Bs[srow   ][skoff] = b0;
        __syncthreads();
        bf8_t af[2], bfr[4];
#pragma unroll
        for (int i=0;i<2;i++) af[i]  = *(const bf8_t*)&As[wave*32 + i*16 + l15][quad*8];
#pragma unroll
        for (int j=0;j<4;j++) bfr[j] = *(const bf8_t*)&Bs[j*16 + l15][quad*8];
#pragma unroll
        for (int i=0;i<2;i++)
#pragma unroll
          for (int j=0;j<4;j++)
            acc[i][j] = __builtin_amdgcn_mfma_f32_16x16x32_bf16(af[i], bfr[j], acc[i][j], 0,0,0);
    }
    float cs[4], cd[4];
#pragma unroll
    for (int j=0;j<4;j++){ cs[j] = a2s[j*16 + l15]; cd[j] = a2d[j*16 + l15]; }
#pragma unroll
    for (int i=0;i<2;i++){
        int rowb = r0 + wave*32 + i*16 + quad*4;
#pragma unroll
        for (int reg=0; reg<4; reg++){
            int row = rowb + reg;
            bool valid = row < NNODES;
            float sp=0.f, dp=0.f;
#pragma unroll
            for (int j=0;j<4;j++){
                float v = acc[i][j][reg];
                sp += v*cs[j]; dp += v*cd[j];
                if (valid) h2b[(size_t)row*64 + j*16 + l15] = (short)f2bf(v);
            }
            sp += __shfl_xor(sp,1); sp += __shfl_xor(sp,2); sp += __shfl_xor(sp,4); sp += __shfl_xor(sp,8);
            dp += __shfl_xor(dp,1); dp += __shfl_xor(dp,2); dp += __shfl_xor(dp,4); dp += __shfl_xor(dp,8);
            if (valid && l15 == 0){ as2[row] = sp; ad2[row] = dp; }
        }
    }
}

// ---------------- attention aggregation (single-pass, unroll-4) ------------
// Layer 1 gathers fp8 h1 decoded with HW v_cvt_pk_f32_fp8 (2 vals/inst).

__global__ __launch_bounds__(256) void aggregate1_k(const unsigned char* __restrict__ h1f8,
        const float* __restrict__ as1, const float* __restrict__ ad1,
        const int* __restrict__ offsets, const int* __restrict__ srclist,
        const float* __restrict__ b1, short* __restrict__ out1b){
    int d = blockIdx.x*4 + (threadIdx.x >> 6);
    int lane = threadIdx.x & 63;
    if (d >= NNODES) return;
    int hh = lane >> 3;
    int start = offsets[d], end = offsets[d+1];
    float ad_h = ad1[d*8 + hh];
    float denom = 0.f;
    float4 acc = make_float4(0.f,0.f,0.f,0.f);
    int k = start;
    for (; k + 3 < end; k += 4){
        int s0 = srclist[k], s1 = srclist[k+1], s2 = srclist[k+2], s3 = srclist[k+3];
        float e0 = as1[s0*8 + hh] + ad_h;
        float e1 = as1[s1*8 + hh] + ad_h;
        float e2 = as1[s2*8 + hh] + ad_h;
        float e3 = as1[s3*8 + hh] + ad_h;
        unsigned w0 = *(const unsigned*)(h1f8 + (size_t)s0*256 + lane*4);
        unsigned w1 = *(const unsigned*)(h1f8 + (size_t)s1*256 + lane*4);
        unsigned w2 = *(const unsigned*)(h1f8 + (size_t)s2*256 + lane*4);
        unsigned w3 = *(const unsigned*)(h1f8 + (size_t)s3*256 + lane*4);
        e0 = (e0 > 0.f) ? e0 : 0.2f*e0;
        e1 = (e1 > 0.f) ? e1 : 0.2f*e1;
        e2 = (e2 > 0.f) ? e2 : 0.2f*e2;
        e3 = (e3 > 0.f) ? e3 : 0.2f*e3;
        float p0 = __expf(e0), p1 = __expf(e1), p2 = __expf(e2), p3 = __expf(e3);
        denom += (p0 + p1) + (p2 + p3);
        f2_t lo0 = __builtin_amdgcn_cvt_pk_f32_fp8(w0, false), hi0 = __builtin_amdgcn_cvt_pk_f32_fp8(w0, true);
        f2_t lo1 = __builtin_amdgcn_cvt_pk_f32_fp8(w1, false), hi1 = __builtin_amdgcn_cvt_pk_f32_fp8(w1, true);
        f2_t lo2 = __builtin_amdgcn_cvt_pk_f32_fp8(w2, false), hi2 = __builtin_amdgcn_cvt_pk_f32_fp8(w2, true);
        f2_t lo3 = __builtin_amdgcn_cvt_pk_f32_fp8(w3, false), hi3 = __builtin_amdgcn_cvt_pk_f32_fp8(w3, true);
        acc.x += p0*lo0[0] + p1*lo1[0] + p2*lo2[0] + p3*lo3[0];
        acc.y += p0*lo0[1] + p1*lo1[1] + p2*lo2[1] + p3*lo3[1];
        acc.z += p0*hi0[0] + p1*hi1[0] + p2*hi2[0] + p3*hi3[0];
        acc.w += p0*hi0[1] + p1*hi1[1] + p2*hi2[1] + p3*hi3[1];
    }
    for (; k < end; k++){
        int s0 = srclist[k];
        float e0 = as1[s0*8 + hh] + ad_h;
        unsigned w0 = *(const unsigned*)(h1f8 + (size_t)s0*256 + lane*4);
        e0 = (e0 > 0.f) ? e0 : 0.2f*e0;
        float p0 = __expf(e0);
        denom += p0;
        f2_t lo0 = __builtin_amdgcn_cvt_pk_f32_fp8(w0, false), hi0 = __builtin_amdgcn_cvt_pk_f32_fp8(w0, true);
        acc.x += p0*lo0[0]; acc.y += p0*lo0[1];
        acc.z += p0*hi0[0]; acc.w += p0*hi0[1];
    }
    float inv = 1.f / denom;
    float4 bv = *(const float4*)(b1 + lane*4);
    ushort4 us;
    us.x = f2bf(fmaxf(acc.x*inv + bv.x, 0.f));
    us.y = f2bf(fmaxf(acc.y*inv + bv.y, 0.f));
    us.z = f2bf(fmaxf(acc.z*inv + bv.z, 0.f));
    us.w = f2bf(fmaxf(acc.w*inv + bv.w, 0.f));
    *(ushort4*)(out1b + (size_t)d*256 + lane*4) = us;
}

__global__ __launch_bounds__(256) void aggregate2_k(const unsigned short* __restrict__ h2b,
        const float* __restrict__ as2, const float* __restrict__ ad2,
        const int* __restrict__ offsets, const int* __restrict__ srclist,
        const float* __restrict__ b2, float* __restrict__ out){
    int d = blockIdx.x*4 + (threadIdx.x >> 6);
    int lane = threadIdx.x & 63;
    if (d >= NNODES) return;
    int start = offsets[d], end = offsets[d+1];
    float ad_v = ad2[d];
    float denom = 0.f, acc = 0.f;
    int k = start;
    for (; k + 3 < end; k += 4){
        int s0 = srclist[k], s1 = srclist[k+1], s2 = srclist[k+2], s3 = srclist[k+3];
        float e0 = as2[s0] + ad_v;
        float e1 = as2[s1] + ad_v;
        float e2 = as2[s2] + ad_v;
        float e3 = as2[s3] + ad_v;
        unsigned short u0 = h2b[(size_t)s0*64 + lane];
        unsigned short u1 = h2b[(size_t)s1*64 + lane];
        unsigned short u2 = h2b[(size_t)s2*64 + lane];
        unsigned short u3 = h2b[(size_t)s3*64 + lane];
        e0 = (e0 > 0.f) ? e0 : 0.2f*e0;
        e1 = (e1 > 0.f) ? e1 : 0.2f*e1;
        e2 = (e2 > 0.f) ? e2 : 0.2f*e2;
        e3 = (e3 > 0.f) ? e3 : 0.2f*e3;
        float p0 = __expf(e0), p1 = __expf(e1), p2 = __expf(e2), p3 = __expf(e3);
        denom += (p0 + p1) + (p2 + p3);
        acc += p0*bf2f(u0) + p1*bf2f(u1) + p2*bf2f(u2) + p3*bf2f(u3);
    }
    for (; k < end; k++){
        int s0 = srclist[k];
        float e0 = as2[s0] + ad_v;
        unsigned short u0 = h2b[(size_t)s0*64 + lane];
        e0 = (e0 > 0.f) ? e0 : 0.2f*e0;
        float p0 = __expf(e0);
        denom += p0;
        acc += p0*bf2f(u0);
    }
    float v = acc/denom + b2[lane];
    float mx = v;
#pragma unroll
    for (int off = 1; off < 64; off <<= 1) mx = fmaxf(mx, __shfl_xor(mx, off));
    float ex = __expf(v - mx);
    float ss = ex;
#pragma unroll
    for (int off = 1; off < 64; off <<= 1) ss += __shfl_xor(ss, off);
    out[(size_t)d*64 + lane] = v - mx - __logf(ss);
}

// ---------------- launch ----------------

extern "C" void kernel_launch(void* const* d_in, const int* in_sizes, int n_in,
                              void* d_out, int out_size, void* d_ws, size_t ws_size,
                              hipStream_t stream){
    const float* x      = (const float*)d_in[0];
    const int*   ei     = (const int*)  d_in[1];
    const float* W1     = (const float*)d_in[2];
    const float* a_src1 = (const float*)d_in[3];
    const float* a_dst1 = (const float*)d_in[4];
    const float* b1     = (const float*)d_in[5];
    const float* W2     = (const float*)d_in[6];
    const float* a_src2 = (const float*)d_in[7];
    const float* a_dst2 = (const float*)d_in[8];
    const float* b2     = (const float*)d_in[9];

    char* ws = (char*)d_ws;
    int*   offsets = (int*)  (ws + OFF_OFFSETS);
    int*   bsums   = (int*)  (ws + OFF_BSUMS);
    int*   cursor  = (int*)  (ws + OFF_CURSOR);
    int*   srclist = (int*)  (ws + OFF_SRC);
    float* as1     = (float*)(ws + OFF_AS1);
    float* ad1     = (float*)(ws + OFF_AD1);
    short* w1t     = (short*)(ws + OFF_W1T);
    short* w2t     = (short*)(ws + OFF_W2T);
    unsigned char* h1f8 = (unsigned char*)(ws + OFF_H1F8);
    short* out1b   = (short*)(ws + OFF_OUT1B);
    short* h2b     = (short*)(ws + OFF_H2B);
    float* as2     = (float*)(ws + OFF_AS2);
    float* ad2     = (float*)(ws + OFF_AD2);

    // CSR by dst
    hipMemsetAsync(offsets, 0, (NNODES+1)*sizeof(int), stream);
    degree_k    <<<(ETOT+255)/256, 256, 0, stream>>>(ei, offsets);
    scan_block_k<<<NB_SCAN, 256, 0, stream>>>(offsets, bsums);
    scan_top_k  <<<1, 256, 0, stream>>>(bsums);
    scan_add_k  <<<NB_SCAN, 256, 0, stream>>>(offsets, bsums, cursor);
    scatter_k   <<<(ETOT+255)/256, 256, 0, stream>>>(ei, cursor, srclist);

    // weight prep (one launch for both layers)
    conv_w_k<<<(256*256 + 64*256 + 255)/256, 256, 0, stream>>>(W1, W2, w1t, w2t);

    // Layer 1
    gemm1_mfma<<<(NNODES+127)/128, 512, 0, stream>>>(x, w1t, a_src1, a_dst1, h1f8, as1, ad1);
    aggregate1_k<<<(NNODES+3)/4, 256, 0, stream>>>(h1f8, as1, ad1, offsets, srclist, b1, out1b);

    // Layer 2
    gemm2_mfma<<<(NNODES+127)/128, 256, 0, stream>>>(out1b, w2t, a_src2, a_dst2, h2b, as2, ad2);
    aggregate2_k<<<(NNODES+3)/4, 256, 0, stream>>>((const unsigned short*)h2b, as2, ad2, offsets, srclist, b2, (float*)d_out);
}

// Round 7
// 273.319 us; speedup vs baseline: 1.3412x; 1.2044x over previous
//
#include <hip/hip_runtime.h>
#include <math.h>

#define NNODES 50000
#define EORIG  800000
#define ETOT   850000     // EORIG + NNODES self loops
#define NBUCK  196        // ceil(NNODES/256) buckets of 256 nodes (bucket = dst>>8)
#define P2CHUNK 4096      // edges per partition block
#define NBLK2  ((ETOT + P2CHUNK - 1)/P2CHUNK)   // 208

typedef __attribute__((ext_vector_type(8))) short bf8_t;   // 8 bf16 (bits in shorts)
typedef __attribute__((ext_vector_type(4))) float f4_t;
typedef __attribute__((ext_vector_type(2))) float f2_t;

constexpr size_t align256(size_t x){ return (x + 255) & ~size_t(255); }
constexpr size_t OFF_OFFSETS = 0;                                           // (N+1) ints
constexpr size_t OFF_BCNT    = OFF_OFFSETS + align256((NNODES+1)*4);        // NBUCK ints
constexpr size_t OFF_BSTART  = OFF_BCNT    + align256(NBUCK*4);             // NBUCK+1 ints
constexpr size_t OFF_GCUR    = OFF_BSTART  + align256((NBUCK+1)*4);         // NBUCK ints
constexpr size_t OFF_EPACK   = OFF_GCUR    + align256(NBUCK*4);             // ETOT ints
constexpr size_t OFF_SRC     = OFF_EPACK   + align256((size_t)ETOT*4);      // ETOT ints
constexpr size_t OFF_AS1     = OFF_SRC     + align256((size_t)ETOT*4);      // N*8 f32
constexpr size_t OFF_AD1     = OFF_AS1     + align256((size_t)NNODES*8*4);
constexpr size_t OFF_W1T     = OFF_AD1     + align256((size_t)NNODES*8*4);  // 256*256 bf16 (n-major)
constexpr size_t OFF_W2T     = OFF_W1T     + align256(256*256*2);           // 64*256 bf16 (n-major)
constexpr size_t OFF_H1F8    = OFF_W2T     + align256(64*256*2);            // N*256 fp8
constexpr size_t OFF_OUT1B   = OFF_H1F8    + align256((size_t)NNODES*256);  // N*256 bf16
// h2b overlays dead h1f8 after aggregate1
constexpr size_t OFF_H2B     = OFF_H1F8;                                    // N*64 bf16
constexpr size_t OFF_AS2     = OFF_OUT1B   + align256((size_t)NNODES*256*2);
constexpr size_t OFF_AD2     = OFF_AS2     + align256((size_t)NNODES*4);

__device__ __forceinline__ unsigned short f2bf(float f){
    union { float f; unsigned u; } v; v.f = f;
    unsigned r = v.u + 0x7FFF + ((v.u >> 16) & 1);   // RNE
    return (unsigned short)(r >> 16);
}
__device__ __forceinline__ float bf2f(unsigned short s){
    union { unsigned u; float f; } v; v.u = ((unsigned)s) << 16;
    return v.f;
}

// ---------------- CSR construction: LDS multisplit, no per-edge global atomics

// Pass 1: global bucket histogram (LDS-staged)
__global__ __launch_bounds__(256) void p1_hist(const int* __restrict__ ei, int* __restrict__ gbcount){
    __shared__ int h[NBUCK];
    for (int i = threadIdx.x; i < NBUCK; i += 256) h[i] = 0;
    __syncthreads();
    int base = blockIdx.x * P2CHUNK;
#pragma unroll
    for (int j = 0; j < P2CHUNK/256; j++){
        int e = base + j*256 + threadIdx.x;
        if (e < ETOT){
            int dst = (e < EORIG) ? ei[EORIG + e] : (e - EORIG);
            atomicAdd(&h[dst >> 8], 1);
        }
    }
    __syncthreads();
    for (int i = threadIdx.x; i < NBUCK; i += 256)
        if (h[i]) atomicAdd(&gbcount[i], h[i]);
}

// Pass 2: exclusive scan of bucket counts -> bstart, init bucket cursors
__global__ __launch_bounds__(256) void p2_scan(const int* __restrict__ gbcount,
                                               int* __restrict__ bstart, int* __restrict__ gcur){
    __shared__ int sm[256];
    int t = threadIdx.x;
    int v = (t < NBUCK) ? gbcount[t] : 0;
    sm[t] = v; __syncthreads();
    for (int off = 1; off < 256; off <<= 1){
        int add = (t >= off) ? sm[t-off] : 0;
        __syncthreads();
        sm[t] += add;
        __syncthreads();
    }
    int excl = sm[t] - v;
    if (t < NBUCK){ bstart[t] = excl; gcur[t] = excl; }
    if (t == NBUCK-1) bstart[NBUCK] = excl + v;   // = ETOT
}

// Pass 3: block-level multisplit into bucket-contiguous packed array
// epack = (src<<8) | (dst & 255);  src < 50000 fits in 24 bits.
__global__ __launch_bounds__(256) void p3_part(const int* __restrict__ ei, int* __restrict__ gcur,
                                               int* __restrict__ epack){
    __shared__ int h[NBUCK];    // block hist -> block base per bucket
    __shared__ int r[NBUCK];    // intra-block rank cursor
    const int t = threadIdx.x;
    for (int i = t; i < NBUCK; i += 256){ h[i] = 0; r[i] = 0; }
    __syncthreads();
    const int base = blockIdx.x * P2CHUNK;
    int srcs[P2CHUNK/256], dsts[P2CHUNK/256];
#pragma unroll
    for (int j = 0; j < P2CHUNK/256; j++){
        int e = base + j*256 + t;
        if (e < ETOT){
            if (e < EORIG){ srcs[j] = ei[e]; dsts[j] = ei[EORIG + e]; }
            else          { srcs[j] = dsts[j] = e - EORIG; }
            atomicAdd(&h[dsts[j] >> 8], 1);
        } else dsts[j] = -1;
    }
    __syncthreads();
    for (int i = t; i < NBUCK; i += 256){
        int c = h[i];
        h[i] = c ? atomicAdd(&gcur[i], c) : 0;
    }
    __syncthreads();
#pragma unroll
    for (int j = 0; j < P2CHUNK/256; j++){
        if (dsts[j] >= 0){
            int b = dsts[j] >> 8;
            int rk = atomicAdd(&r[b], 1);
            epack[h[b] + rk] = (srcs[j] << 8) | (dsts[j] & 255);
        }
    }
}

// Pass 4: one block per bucket -> local CSR in LDS, coalesced offsets,
// srclist writes confined to the bucket's contiguous region (one XCD L2).
__global__ __launch_bounds__(256) void p4_csr(const int* __restrict__ bstart, const int* __restrict__ epack,
                                              int* __restrict__ offsets, int* __restrict__ srclist){
    __shared__ int deg[256];
    __shared__ int sm[256];
    __shared__ int cur[256];
    const int b = blockIdx.x, t = threadIdx.x;
    const int s0 = bstart[b], s1 = bstart[b+1];
    deg[t] = 0; __syncthreads();
    for (int i = s0 + t; i < s1; i += 256) atomicAdd(&deg[epack[i] & 255], 1);
    __syncthreads();
    int v = deg[t];
    sm[t] = v; __syncthreads();
    for (int off = 1; off < 256; off <<= 1){
        int add = (t >= off) ? sm[t-off] : 0;
        __syncthreads();
        sm[t] += add;
        __syncthreads();
    }
    int excl = sm[t] - v;
    int node = (b << 8) + t;
    if (node <= NNODES) offsets[node] = s0 + excl;   // node==NNODES lands on ETOT naturally
    cur[t] = s0 + excl;
    __syncthreads();
    for (int i = s0 + t; i < s1; i += 256){
        int p = epack[i];
        int pos = atomicAdd(&cur[p & 255], 1);
        srclist[pos] = p >> 8;
    }
}

// ---------------- weight transpose+convert (both layers, one launch) -------

__global__ __launch_bounds__(256) void conv_w_k(const float* __restrict__ W1, const float* __restrict__ W2,
                                                short* __restrict__ w1t, short* __restrict__ w2t){
    int o = blockIdx.x*256 + threadIdx.x;
    if (o < 256*256){
        int n = o >> 8, k = o & 255;
        w1t[o] = (short)f2bf(W1[k*256 + n]);
    } else {
        int o2 = o - 256*256;
        if (o2 < 64*256){
            int n = o2 >> 8, k = o2 & 255;
            w2t[o2] = (short)f2bf(W2[k*64 + n]);
        }
    }
}

// ---------------- GEMM1 (MFMA): h1f8 = fp8(x @ W1), fused f32->bf16 A-stage
// + fused as1/ad1 epilogue.  128x256 tile, 512 threads = 2x4 waves, BK=32.

__global__ __launch_bounds__(512) void gemm1_mfma(const float* __restrict__ x, const short* __restrict__ w1t,
        const float* __restrict__ a1s, const float* __restrict__ a1d,
        unsigned char* __restrict__ h1f8, float* __restrict__ as1, float* __restrict__ ad1){
    __shared__ short As[128][40];   // +8 pad: 16B-aligned frags, 2-way banks = free
    __shared__ short Bs[256][40];   // Bs[n][k] (from pre-transposed W1T)
    const int t = threadIdx.x;                 // 0..511
    const int lane = t & 63, wave = t >> 6;    // 8 waves
    const int wy = wave >> 2, wx = wave & 3;   // 2 x 4 wave grid
    const int quad = lane >> 4, l15 = lane & 15;
    const int r0 = blockIdx.x * 128;
    const int srow = t >> 2, skoff = (t & 3) * 8;   // srow 0..127
    f4_t zero4 = {0.f,0.f,0.f,0.f};
    f4_t acc[4][4];
#pragma unroll
    for (int i=0;i<4;i++)
#pragma unroll
      for (int j=0;j<4;j++) acc[i][j] = zero4;

    for (int kk = 0; kk < 256; kk += 32){
        float4 xa0 = {0,0,0,0}, xa1 = {0,0,0,0};
        if (r0 + srow < NNODES){
            xa0 = *(const float4*)(x + (size_t)(r0+srow)*256 + kk + skoff);
            xa1 = *(const float4*)(x + (size_t)(r0+srow)*256 + kk + skoff + 4);
        }
        bf8_t b0  = *(const bf8_t*)(w1t + (size_t)(srow      )*256 + kk + skoff);
        bf8_t b1v = *(const bf8_t*)(w1t + (size_t)(srow + 128)*256 + kk + skoff);
        bf8_t a0;
        a0[0]=f2bf(xa0.x); a0[1]=f2bf(xa0.y); a0[2]=f2bf(xa0.z); a0[3]=f2bf(xa0.w);
        a0[4]=f2bf(xa1.x); a0[5]=f2bf(xa1.y); a0[6]=f2bf(xa1.z); a0[7]=f2bf(xa1.w);
        __syncthreads();
        *(bf8_t*)&As[srow     ][skoff] = a0;
        *(bf8_t*)&Bs[srow     ][skoff] = b0;
        *(bf8_t*)&Bs[srow+128][skoff] = b1v;
        __syncthreads();
        bf8_t af[4], bfr[4];
#pragma unroll
        for (int i=0;i<4;i++) af[i]  = *(const bf8_t*)&As[wy*64 + i*16 + l15][quad*8];
#pragma unroll
        for (int j=0;j<4;j++) bfr[j] = *(const bf8_t*)&Bs[wx*64 + j*16 + l15][quad*8];
#pragma unroll
        for (int i=0;i<4;i++)
#pragma unroll
          for (int j=0;j<4;j++)
            acc[i][j] = __builtin_amdgcn_mfma_f32_16x16x32_bf16(af[i], bfr[j], acc[i][j], 0,0,0);
    }
    // epilogue: fp8 store (HW cvt, OCP e4m3fn) + fused alpha projections
    const int colbase = wx*64;               // this wave's 64 cols = 2 heads
    const int head0 = colbase >> 5;
    float cs[4], cd[4];
#pragma unroll
    for (int j=0;j<4;j++){ cs[j] = a1s[colbase + j*16 + l15]; cd[j] = a1d[colbase + j*16 + l15]; }
#pragma unroll
    for (int i=0;i<4;i++){
        int rowb = r0 + wy*64 + i*16 + quad*4;
#pragma unroll
        for (int reg=0; reg<4; reg++){
            int row = rowb + reg;
            bool valid = row < NNODES;
            float sp0=0.f, dp0=0.f, sp1=0.f, dp1=0.f;
#pragma unroll
            for (int j=0;j<4;j++){
                float v = acc[i][j][reg];
                if (j < 2){ sp0 += v*cs[j]; dp0 += v*cd[j]; }
                else      { sp1 += v*cs[j]; dp1 += v*cd[j]; }
                if (valid){
                    unsigned enc = (unsigned)__builtin_amdgcn_cvt_pk_fp8_f32(v, v, 0, false);
                    h1f8[(size_t)row*256 + colbase + j*16 + l15] = (unsigned char)(enc & 0xffu);
                }
            }
            sp0 += __shfl_xor(sp0,1); sp0 += __shfl_xor(sp0,2); sp0 += __shfl_xor(sp0,4); sp0 += __shfl_xor(sp0,8);
            dp0 += __shfl_xor(dp0,1); dp0 += __shfl_xor(dp0,2); dp0 += __shfl_xor(dp0,4); dp0 += __shfl_xor(dp0,8);
            sp1 += __shfl_xor(sp1,1); sp1 += __shfl_xor(sp1,2); sp1 += __shfl_xor(sp1,4); sp1 += __shfl_xor(sp1,8);
            dp1 += __shfl_xor(dp1,1); dp1 += __shfl_xor(dp1,2); dp1 += __shfl_xor(dp1,4); dp1 += __shfl_xor(dp1,8);
            if (valid && l15 == 0){
                as1[row*8 + head0    ] = sp0;
                ad1[row*8 + head0    ] = dp0;
                as1[row*8 + head0 + 1] = sp1;
                ad1[row*8 + head0 + 1] = dp1;
            }
        }
    }
}

// ---------------- GEMM2 (MFMA): h2b = bf16(out1b @ W2), fused as2/ad2 ------

__global__ __launch_bounds__(256) void gemm2_mfma(const short* __restrict__ ab, const short* __restrict__ w2t,
        const float* __restrict__ a2s, const float* __restrict__ a2d,
        short* __restrict__ h2b, float* __restrict__ as2, float* __restrict__ ad2){
    __shared__ short As[128][40];
    __shared__ short Bs[64][40];
    const int t = threadIdx.x;
    const int lane = t & 63, wave = t >> 6;
    const int quad = lane >> 4, l15 = lane & 15;
    const int r0 = blockIdx.x * 128;
    const int srow = t >> 2, skoff = (t & 3) * 8;
    f4_t zero4 = {0.f,0.f,0.f,0.f};
    f4_t acc[2][4];
#pragma unroll
    for (int i=0;i<2;i++)
#pragma unroll
      for (int j=0;j<4;j++) acc[i][j] = zero4;

    for (int kk = 0; kk < 256; kk += 32){
        bf8_t a0 = {}, a1v = {};
        if (r0 + srow < NNODES)      a0  = *(const bf8_t*)(ab + (size_t)(r0+srow)*256 + kk + skoff);
        if (r0 + srow + 64 < NNODES) a1v = *(const bf8_t*)(ab + (size_t)(r0+srow+64)*256 + kk + skoff);
        bf8_t b0 = *(const bf8_t*)(w2t + (size_t)srow*256 + kk + skoff);   // srow = n (0..63)
        __syncthreads();
        *(bf8_t*)&As[srow   ][skoff] = a0;
        *(bf8_t*)&As[srow+64][skoff] = a1v;
        *(bf8_t*)&Bs[srow   ][skoff] = b0;
        __syncthreads();
        bf8_t af[2], bfr[4];
#pragma unroll
        for (int i=0;i<2;i++) af[i]  = *(const bf8_t*)&As[wave*32 + i*16 + l15][quad*8];
#pragma unroll
        for (int j=0;j<4;j++) bfr[j] = *(const bf8_t*)&Bs[j*16 + l15][quad*8];
#pragma unroll
        for (int i=0;i<2;i++)
#pragma unroll
          for (int j=0;j<4;j++)
            acc[i][j] = __builtin_amdgcn_mfma_f32_16x16x32_bf16(af[i], bfr[j], acc[i][j], 0,0,0);
    }
    float cs[4], cd[4];
#pragma unroll
    for (int j=0;j<4;j++){ cs[j] = a2s[j*16 + l15]; cd[j] = a2d[j*16 + l15]; }
#pragma unroll
    for (int i=0;i<2;i++){
        int rowb = r0 + wave*32 + i*16 + quad*4;
#pragma unroll
        for (int reg=0; reg<4; reg++){
            int row = rowb + reg;
            bool valid = row < NNODES;
            float sp=0.f, dp=0.f;
#pragma unroll
            for (int j=0;j<4;j++){
                float v = acc[i][j][reg];
                sp += v*cs[j]; dp += v*cd[j];
                if (valid) h2b[(size_t)row*64 + j*16 + l15] = (short)f2bf(v);
            }
            sp += __shfl_xor(sp,1); sp += __shfl_xor(sp,2); sp += __shfl_xor(sp,4); sp += __shfl_xor(sp,8);
            dp += __shfl_xor(dp,1); dp += __shfl_xor(dp,2); dp += __shfl_xor(dp,4); dp += __shfl_xor(dp,8);
            if (valid && l15 == 0){ as2[row] = sp; ad2[row] = dp; }
        }
    }
}

// ---------------- attention aggregation (single-pass, unroll-4) ------------

__global__ __launch_bounds__(256) void aggregate1_k(const unsigned char* __restrict__ h1f8,
        const float* __restrict__ as1, const float* __restrict__ ad1,
        const int* __restrict__ offsets, const int* __restrict__ srclist,
        const float* __restrict__ b1, short* __restrict__ out1b){
    int d = blockIdx.x*4 + (threadIdx.x >> 6);
    int lane = threadIdx.x & 63;
    if (d >= NNODES) return;
    int hh = lane >> 3;
    int start = offsets[d], end = offsets[d+1];
    float ad_h = ad1[d*8 + hh];
    float denom = 0.f;
    float4 acc = make_float4(0.f,0.f,0.f,0.f);
    int k = start;
    for (; k + 3 < end; k += 4){
        int s0 = srclist[k], s1 = srclist[k+1], s2 = srclist[k+2], s3 = srclist[k+3];
        float e0 = as1[s0*8 + hh] + ad_h;
        float e1 = as1[s1*8 + hh] + ad_h;
        float e2 = as1[s2*8 + hh] + ad_h;
        float e3 = as1[s3*8 + hh] + ad_h;
        unsigned w0 = *(const unsigned*)(h1f8 + (size_t)s0*256 + lane*4);
        unsigned w1 = *(const unsigned*)(h1f8 + (size_t)s1*256 + lane*4);
        unsigned w2 = *(const unsigned*)(h1f8 + (size_t)s2*256 + lane*4);
        unsigned w3 = *(const unsigned*)(h1f8 + (size_t)s3*256 + lane*4);
        e0 = (e0 > 0.f) ? e0 : 0.2f*e0;
        e1 = (e1 > 0.f) ? e1 : 0.2f*e1;
        e2 = (e2 > 0.f) ? e2 : 0.2f*e2;
        e3 = (e3 > 0.f) ? e3 : 0.2f*e3;
        float p0 = __expf(e0), p1 = __expf(e1), p2 = __expf(e2), p3 = __expf(e3);
        denom += (p0 + p1) + (p2 + p3);
        f2_t lo0 = __builtin_amdgcn_cvt_pk_f32_fp8(w0, false), hi0 = __builtin_amdgcn_cvt_pk_f32_fp8(w0, true);
        f2_t lo1 = __builtin_amdgcn_cvt_pk_f32_fp8(w1, false), hi1 = __builtin_amdgcn_cvt_pk_f32_fp8(w1, true);
        f2_t lo2 = __builtin_amdgcn_cvt_pk_f32_fp8(w2, false), hi2 = __builtin_amdgcn_cvt_pk_f32_fp8(w2, true);
        f2_t lo3 = __builtin_amdgcn_cvt_pk_f32_fp8(w3, false), hi3 = __builtin_amdgcn_cvt_pk_f32_fp8(w3, true);
        acc.x += p0*lo0[0] + p1*lo1[0] + p2*lo2[0] + p3*lo3[0];
        acc.y += p0*lo0[1] + p1*lo1[1] + p2*lo2[1] + p3*lo3[1];
        acc.z += p0*hi0[0] + p1*hi1[0] + p2*hi2[0] + p3*hi3[0];
        acc.w += p0*hi0[1] + p1*hi1[1] + p2*hi2[1] + p3*hi3[1];
    }
    for (; k < end; k++){
        int s0 = srclist[k];
        float e0 = as1[s0*8 + hh] + ad_h;
        unsigned w0 = *(const unsigned*)(h1f8 + (size_t)s0*256 + lane*4);
        e0 = (e0 > 0.f) ? e0 : 0.2f*e0;
        float p0 = __expf(e0);
        denom += p0;
        f2_t lo0 = __builtin_amdgcn_cvt_pk_f32_fp8(w0, false), hi0 = __builtin_amdgcn_cvt_pk_f32_fp8(w0, true);
        acc.x += p0*lo0[0]; acc.y += p0*lo0[1];
        acc.z += p0*hi0[0]; acc.w += p0*hi0[1];
    }
    float inv = 1.f / denom;
    float4 bv = *(const float4*)(b1 + lane*4);
    ushort4 us;
    us.x = f2bf(fmaxf(acc.x*inv + bv.x, 0.f));
    us.y = f2bf(fmaxf(acc.y*inv + bv.y, 0.f));
    us.z = f2bf(fmaxf(acc.z*inv + bv.z, 0.f));
    us.w = f2bf(fmaxf(acc.w*inv + bv.w, 0.f));
    *(ushort4*)(out1b + (size_t)d*256 + lane*4) = us;
}

__global__ __launch_bounds__(256) void aggregate2_k(const unsigned short* __restrict__ h2b,
        const float* __restrict__ as2, const float* __restrict__ ad2,
        const int* __restrict__ offsets, const int* __restrict__ srclist,
        const float* __restrict__ b2, float* __restrict__ out){
    int d = blockIdx.x*4 + (threadIdx.x >> 6);
    int lane = threadIdx.x & 63;
    if (d >= NNODES) return;
    int start = offsets[d], end = offsets[d+1];
    float ad_v = ad2[d];
    float denom = 0.f, acc = 0.f;
    int k = start;
    for (; k + 3 < end; k += 4){
        int s0 = srclist[k], s1 = srclist[k+1], s2 = srclist[k+2], s3 = srclist[k+3];
        float e0 = as2[s0] + ad_v;
        float e1 = as2[s1] + ad_v;
        float e2 = as2[s2] + ad_v;
        float e3 = as2[s3] + ad_v;
        unsigned short u0 = h2b[(size_t)s0*64 + lane];
        unsigned short u1 = h2b[(size_t)s1*64 + lane];
        unsigned short u2 = h2b[(size_t)s2*64 + lane];
        unsigned short u3 = h2b[(size_t)s3*64 + lane];
        e0 = (e0 > 0.f) ? e0 : 0.2f*e0;
        e1 = (e1 > 0.f) ? e1 : 0.2f*e1;
        e2 = (e2 > 0.f) ? e2 : 0.2f*e2;
        e3 = (e3 > 0.f) ? e3 : 0.2f*e3;
        float p0 = __expf(e0), p1 = __expf(e1), p2 = __expf(e2), p3 = __expf(e3);
        denom += (p0 + p1) + (p2 + p3);
        acc += p0*bf2f(u0) + p1*bf2f(u1) + p2*bf2f(u2) + p3*bf2f(u3);
    }
    for (; k < end; k++){
        int s0 = srclist[k];
        float e0 = as2[s0] + ad_v;
        unsigned short u0 = h2b[(size_t)s0*64 + lane];
        e0 = (e0 > 0.f) ? e0 : 0.2f*e0;
        float p0 = __expf(e0);
        denom += p0;
        acc += p0*bf2f(u0);
    }
    float v = acc/denom + b2[lane];
    float mx = v;
#pragma unroll
    for (int off = 1; off < 64; off <<= 1) mx = fmaxf(mx, __shfl_xor(mx, off));
    float ex = __expf(v - mx);
    float ss = ex;
#pragma unroll
    for (int off = 1; off < 64; off <<= 1) ss += __shfl_xor(ss, off);
    out[(size_t)d*64 + lane] = v - mx - __logf(ss);
}

// ---------------- launch ----------------

extern "C" void kernel_launch(void* const* d_in, const int* in_sizes, int n_in,
                              void* d_out, int out_size, void* d_ws, size_t ws_size,
                              hipStream_t stream){
    const float* x      = (const float*)d_in[0];
    const int*   ei     = (const int*)  d_in[1];
    const float* W1     = (const float*)d_in[2];
    const float* a_src1 = (const float*)d_in[3];
    const float* a_dst1 = (const float*)d_in[4];
    const float* b1     = (const float*)d_in[5];
    const float* W2     = (const float*)d_in[6];
    const float* a_src2 = (const float*)d_in[7];
    const float* a_dst2 = (const float*)d_in[8];
    const float* b2     = (const float*)d_in[9];

    char* ws = (char*)d_ws;
    int*   offsets = (int*)  (ws + OFF_OFFSETS);
    int*   gbcount = (int*)  (ws + OFF_BCNT);
    int*   bstart  = (int*)  (ws + OFF_BSTART);
    int*   gcur    = (int*)  (ws + OFF_GCUR);
    int*   epack   = (int*)  (ws + OFF_EPACK);
    int*   srclist = (int*)  (ws + OFF_SRC);
    float* as1     = (float*)(ws + OFF_AS1);
    float* ad1     = (float*)(ws + OFF_AD1);
    short* w1t     = (short*)(ws + OFF_W1T);
    short* w2t     = (short*)(ws + OFF_W2T);
    unsigned char* h1f8 = (unsigned char*)(ws + OFF_H1F8);
    short* out1b   = (short*)(ws + OFF_OUT1B);
    short* h2b     = (short*)(ws + OFF_H2B);
    float* as2     = (float*)(ws + OFF_AS2);
    float* ad2     = (float*)(ws + OFF_AD2);

    // CSR by dst: LDS multisplit (no per-edge global atomics)
    hipMemsetAsync(gbcount, 0, NBUCK*sizeof(int), stream);
    p1_hist<<<NBLK2, 256, 0, stream>>>(ei, gbcount);
    p2_scan<<<1, 256, 0, stream>>>(gbcount, bstart, gcur);
    p3_part<<<NBLK2, 256, 0, stream>>>(ei, gcur, epack);
    p4_csr <<<NBUCK, 256, 0, stream>>>(bstart, epack, offsets, srclist);

    // weight prep (one launch for both layers)
    conv_w_k<<<(256*256 + 64*256 + 255)/256, 256, 0, stream>>>(W1, W2, w1t, w2t);

    // Layer 1
    gemm1_mfma<<<(NNODES+127)/128, 512, 0, stream>>>(x, w1t, a_src1, a_dst1, h1f8, as1, ad1);
    aggregate1_k<<<(NNODES+3)/4, 256, 0, stream>>>(h1f8, as1, ad1, offsets, srclist, b1, out1b);

    // Layer 2
    gemm2_mfma<<<(NNODES+127)/128, 256, 0, stream>>>(out1b, w2t, a_src2, a_dst2, h2b, as2, ad2);
    aggregate2_k<<<(NNODES+3)/4, 256, 0, stream>>>((const unsigned short*)h2b, as2, ad2, offsets, srclist, b2, (float*)d_out);
}

// Round 8
// 262.473 us; speedup vs baseline: 1.3966x; 1.0413x over previous
//
#include <hip/hip_runtime.h>
#include <math.h>

#define NNODES 50000
#define EORIG  800000
#define ETOT   850000     // EORIG + NNODES self loops
#define NBUCK  196        // ceil(NNODES/256) buckets of 256 nodes (bucket = dst>>8)
#define BSTRIDE 5120      // fixed slots per bucket (mean 4352, +12 sigma headroom)
#define P2CHUNK 4096      // edges per partition block
#define NBLK2  ((ETOT + P2CHUNK - 1)/P2CHUNK)   // 208

typedef __attribute__((ext_vector_type(8))) short bf8_t;   // 8 bf16 (bits in shorts)
typedef __attribute__((ext_vector_type(4))) float f4_t;
typedef __attribute__((ext_vector_type(2))) float f2_t;

constexpr float LOG2E = 1.44269504f;

constexpr size_t align256(size_t x){ return (x + 255) & ~size_t(255); }
constexpr size_t OFF_OFFSETS = 0;                                           // N ints
constexpr size_t OFF_DEG     = OFF_OFFSETS + align256((size_t)NNODES*4);    // N ints
constexpr size_t OFF_GCUR    = OFF_DEG     + align256((size_t)NNODES*4);    // NBUCK ints
constexpr size_t OFF_EPACK   = OFF_GCUR    + align256(NBUCK*4);             // NBUCK*BSTRIDE ints
constexpr size_t OFF_SRC     = OFF_EPACK   + align256((size_t)NBUCK*BSTRIDE*4);
constexpr size_t OFF_AS1     = OFF_SRC     + align256((size_t)NBUCK*BSTRIDE*4); // N*8 f32
constexpr size_t OFF_AD1     = OFF_AS1     + align256((size_t)NNODES*8*4);
constexpr size_t OFF_W1T     = OFF_AD1     + align256((size_t)NNODES*8*4);  // 256*256 bf16 (n-major)
constexpr size_t OFF_W2T     = OFF_W1T     + align256(256*256*2);           // 64*256 bf16 (n-major)
constexpr size_t OFF_H1F8    = OFF_W2T     + align256(64*256*2);            // N*256 fp8
constexpr size_t OFF_OUT1B   = OFF_H1F8    + align256((size_t)NNODES*256);  // N*256 bf16
// h2b overlays dead h1f8 after aggregate1
constexpr size_t OFF_H2B     = OFF_H1F8;                                    // N*64 bf16
constexpr size_t OFF_AS2     = OFF_OUT1B   + align256((size_t)NNODES*256*2);
constexpr size_t OFF_AD2     = OFF_AS2     + align256((size_t)NNODES*4);

__device__ __forceinline__ unsigned short f2bf(float f){
    union { float f; unsigned u; } v; v.f = f;
    unsigned r = v.u + 0x7FFF + ((v.u >> 16) & 1);   // RNE
    return (unsigned short)(r >> 16);
}
__device__ __forceinline__ float bf2f(unsigned short s){
    union { unsigned u; float f; } v; v.u = ((unsigned)s) << 16;
    return v.f;
}

// ---------------- CSR construction: LDS multisplit, fixed-stride buckets ---

__global__ __launch_bounds__(256) void ginit(int* __restrict__ gcur){
    int t = threadIdx.x;
    if (t < NBUCK) gcur[t] = t * BSTRIDE;
}

// block-level multisplit into fixed-stride bucket regions
// epack = (src<<8) | (dst & 255);  src < 50000 fits in 24 bits.
__global__ __launch_bounds__(256) void p3_part(const int* __restrict__ ei, int* __restrict__ gcur,
                                               int* __restrict__ epack){
    __shared__ int h[NBUCK];    // block hist -> block base per bucket
    __shared__ int r[NBUCK];    // intra-block rank cursor
    const int t = threadIdx.x;
    for (int i = t; i < NBUCK; i += 256){ h[i] = 0; r[i] = 0; }
    __syncthreads();
    const int base = blockIdx.x * P2CHUNK;
    int srcs[P2CHUNK/256], dsts[P2CHUNK/256];
#pragma unroll
    for (int j = 0; j < P2CHUNK/256; j++){
        int e = base + j*256 + t;
        if (e < ETOT){
            if (e < EORIG){ srcs[j] = ei[e]; dsts[j] = ei[EORIG + e]; }
            else          { srcs[j] = dsts[j] = e - EORIG; }
            atomicAdd(&h[dsts[j] >> 8], 1);
        } else dsts[j] = -1;
    }
    __syncthreads();
    for (int i = t; i < NBUCK; i += 256){
        int c = h[i];
        h[i] = c ? atomicAdd(&gcur[i], c) : 0;
    }
    __syncthreads();
#pragma unroll
    for (int j = 0; j < P2CHUNK/256; j++){
        if (dsts[j] >= 0){
            int b = dsts[j] >> 8;
            int rk = atomicAdd(&r[b], 1);
            epack[h[b] + rk] = (srcs[j] << 8) | (dsts[j] & 255);
        }
    }
}

// one block per bucket -> local CSR in LDS; offsets/deg coalesced;
// srclist writes confined to the bucket's contiguous region.
__global__ __launch_bounds__(256) void p4_csr(const int* __restrict__ gcur, const int* __restrict__ epack,
                                              int* __restrict__ offsets, int* __restrict__ deg_g,
                                              int* __restrict__ srclist){
    __shared__ int deg[256];
    __shared__ int sm[256];
    __shared__ int cur[256];
    const int b = blockIdx.x, t = threadIdx.x;
    const int s0 = b * BSTRIDE, s1 = gcur[b];
    deg[t] = 0; __syncthreads();
    for (int i = s0 + t; i < s1; i += 256) atomicAdd(&deg[epack[i] & 255], 1);
    __syncthreads();
    int v = deg[t];
    sm[t] = v; __syncthreads();
    for (int off = 1; off < 256; off <<= 1){
        int add = (t >= off) ? sm[t-off] : 0;
        __syncthreads();
        sm[t] += add;
        __syncthreads();
    }
    int excl = sm[t] - v;
    int node = (b << 8) + t;
    if (node < NNODES){ offsets[node] = s0 + excl; deg_g[node] = v; }
    cur[t] = s0 + excl;
    __syncthreads();
    for (int i = s0 + t; i < s1; i += 256){
        int p = epack[i];
        int pos = atomicAdd(&cur[p & 255], 1);
        srclist[pos] = p >> 8;
    }
}

// ---------------- weight transpose+convert (both layers, one launch) -------

__global__ __launch_bounds__(256) void conv_w_k(const float* __restrict__ W1, const float* __restrict__ W2,
                                                short* __restrict__ w1t, short* __restrict__ w2t){
    int o = blockIdx.x*256 + threadIdx.x;
    if (o < 256*256){
        int n = o >> 8, k = o & 255;
        w1t[o] = (short)f2bf(W1[k*256 + n]);
    } else {
        int o2 = o - 256*256;
        if (o2 < 64*256){
            int n = o2 >> 8, k = o2 & 255;
            w2t[o2] = (short)f2bf(W2[k*64 + n]);
        }
    }
}

// ---------------- GEMM1 (MFMA): h1f8 = fp8(x @ W1), fused f32->bf16 A-stage
// + fused as1/ad1 epilogue (pre-scaled by log2(e) for exp2-based softmax).
// 128x256 tile, 512 threads = 2x4 waves, BK=32.

__global__ __launch_bounds__(512) void gemm1_mfma(const float* __restrict__ x, const short* __restrict__ w1t,
        const float* __restrict__ a1s, const float* __restrict__ a1d,
        unsigned char* __restrict__ h1f8, float* __restrict__ as1, float* __restrict__ ad1){
    __shared__ short As[128][40];   // +8 pad: 16B-aligned frags, 2-way banks = free
    __shared__ short Bs[256][40];   // Bs[n][k] (from pre-transposed W1T)
    const int t = threadIdx.x;                 // 0..511
    const int lane = t & 63, wave = t >> 6;    // 8 waves
    const int wy = wave >> 2, wx = wave & 3;   // 2 x 4 wave grid
    const int quad = lane >> 4, l15 = lane & 15;
    const int r0 = blockIdx.x * 128;
    const int srow = t >> 2, skoff = (t & 3) * 8;   // srow 0..127
    f4_t zero4 = {0.f,0.f,0.f,0.f};
    f4_t acc[4][4];
#pragma unroll
    for (int i=0;i<4;i++)
#pragma unroll
      for (int j=0;j<4;j++) acc[i][j] = zero4;

    for (int kk = 0; kk < 256; kk += 32){
        float4 xa0 = {0,0,0,0}, xa1 = {0,0,0,0};
        if (r0 + srow < NNODES){
            xa0 = *(const float4*)(x + (size_t)(r0+srow)*256 + kk + skoff);
            xa1 = *(const float4*)(x + (size_t)(r0+srow)*256 + kk + skoff + 4);
        }
        bf8_t b0  = *(const bf8_t*)(w1t + (size_t)(srow      )*256 + kk + skoff);
        bf8_t b1v = *(const bf8_t*)(w1t + (size_t)(srow + 128)*256 + kk + skoff);
        bf8_t a0;
        a0[0]=f2bf(xa0.x); a0[1]=f2bf(xa0.y); a0[2]=f2bf(xa0.z); a0[3]=f2bf(xa0.w);
        a0[4]=f2bf(xa1.x); a0[5]=f2bf(xa1.y); a0[6]=f2bf(xa1.z); a0[7]=f2bf(xa1.w);
        __syncthreads();
        *(bf8_t*)&As[srow     ][skoff] = a0;
        *(bf8_t*)&Bs[srow     ][skoff] = b0;
        *(bf8_t*)&Bs[srow+128][skoff] = b1v;
        __syncthreads();
        bf8_t af[4], bfr[4];
#pragma unroll
        for (int i=0;i<4;i++) af[i]  = *(const bf8_t*)&As[wy*64 + i*16 + l15][quad*8];
#pragma unroll
        for (int j=0;j<4;j++) bfr[j] = *(const bf8_t*)&Bs[wx*64 + j*16 + l15][quad*8];
#pragma unroll
        for (int i=0;i<4;i++)
#pragma unroll
          for (int j=0;j<4;j++)
            acc[i][j] = __builtin_amdgcn_mfma_f32_16x16x32_bf16(af[i], bfr[j], acc[i][j], 0,0,0);
    }
    // epilogue: fp8 store (HW cvt) + fused alpha projections (x log2e)
    const int colbase = wx*64;               // this wave's 64 cols = 2 heads
    const int head0 = colbase >> 5;
    float cs[4], cd[4];
#pragma unroll
    for (int j=0;j<4;j++){
        cs[j] = a1s[colbase + j*16 + l15] * LOG2E;
        cd[j] = a1d[colbase + j*16 + l15] * LOG2E;
    }
#pragma unroll
    for (int i=0;i<4;i++){
        int rowb = r0 + wy*64 + i*16 + quad*4;
#pragma unroll
        for (int reg=0; reg<4; reg++){
            int row = rowb + reg;
            bool valid = row < NNODES;
            float sp0=0.f, dp0=0.f, sp1=0.f, dp1=0.f;
#pragma unroll
            for (int j=0;j<4;j++){
                float v = acc[i][j][reg];
                if (j < 2){ sp0 += v*cs[j]; dp0 += v*cd[j]; }
                else      { sp1 += v*cs[j]; dp1 += v*cd[j]; }
                if (valid){
                    unsigned enc = (unsigned)__builtin_amdgcn_cvt_pk_fp8_f32(v, v, 0, false);
                    h1f8[(size_t)row*256 + colbase + j*16 + l15] = (unsigned char)(enc & 0xffu);
                }
            }
            sp0 += __shfl_xor(sp0,1); sp0 += __shfl_xor(sp0,2); sp0 += __shfl_xor(sp0,4); sp0 += __shfl_xor(sp0,8);
            dp0 += __shfl_xor(dp0,1); dp0 += __shfl_xor(dp0,2); dp0 += __shfl_xor(dp0,4); dp0 += __shfl_xor(dp0,8);
            sp1 += __shfl_xor(sp1,1); sp1 += __shfl_xor(sp1,2); sp1 += __shfl_xor(sp1,4); sp1 += __shfl_xor(sp1,8);
            dp1 += __shfl_xor(dp1,1); dp1 += __shfl_xor(dp1,2); dp1 += __shfl_xor(dp1,4); dp1 += __shfl_xor(dp1,8);
            if (valid && l15 == 0){
                as1[row*8 + head0    ] = sp0;
                ad1[row*8 + head0    ] = dp0;
                as1[row*8 + head0 + 1] = sp1;
                ad1[row*8 + head0 + 1] = dp1;
            }
        }
    }
}

// ---------------- GEMM2 (MFMA): h2b = bf16(out1b @ W2), fused as2/ad2 ------

__global__ __launch_bounds__(256) void gemm2_mfma(const short* __restrict__ ab, const short* __restrict__ w2t,
        const float* __restrict__ a2s, const float* __restrict__ a2d,
        short* __restrict__ h2b, float* __restrict__ as2, float* __restrict__ ad2){
    __shared__ short As[128][40];
    __shared__ short Bs[64][40];
    const int t = threadIdx.x;
    const int lane = t & 63, wave = t >> 6;
    const int quad = lane >> 4, l15 = lane & 15;
    const int r0 = blockIdx.x * 128;
    const int srow = t >> 2, skoff = (t & 3) * 8;
    f4_t zero4 = {0.f,0.f,0.f,0.f};
    f4_t acc[2][4];
#pragma unroll
    for (int i=0;i<2;i++)
#pragma unroll
      for (int j=0;j<4;j++) acc[i][j] = zero4;

    for (int kk = 0; kk < 256; kk += 32){
        bf8_t a0 = {}, a1v = {};
        if (r0 + srow < NNODES)      a0  = *(const bf8_t*)(ab + (size_t)(r0+srow)*256 + kk + skoff);
        if (r0 + srow + 64 < NNODES) a1v = *(const bf8_t*)(ab + (size_t)(r0+srow+64)*256 + kk + skoff);
        bf8_t b0 = *(const bf8_t*)(w2t + (size_t)srow*256 + kk + skoff);   // srow = n (0..63)
        __syncthreads();
        *(bf8_t*)&As[srow   ][skoff] = a0;
        *(bf8_t*)&As[srow+64][skoff] = a1v;
        *(bf8_t*)&Bs[srow   ][skoff] = b0;
        __syncthreads();
        bf8_t af[2], bfr[4];
#pragma unroll
        for (int i=0;i<2;i++) af[i]  = *(const bf8_t*)&As[wave*32 + i*16 + l15][quad*8];
#pragma unroll
        for (int j=0;j<4;j++) bfr[j] = *(const bf8_t*)&Bs[j*16 + l15][quad*8];
#pragma unroll
        for (int i=0;i<2;i++)
#pragma unroll
          for (int j=0;j<4;j++)
            acc[i][j] = __builtin_amdgcn_mfma_f32_16x16x32_bf16(af[i], bfr[j], acc[i][j], 0,0,0);
    }
    float cs[4], cd[4];
#pragma unroll
    for (int j=0;j<4;j++){
        cs[j] = a2s[j*16 + l15] * LOG2E;
        cd[j] = a2d[j*16 + l15] * LOG2E;
    }
#pragma unroll
    for (int i=0;i<2;i++){
        int rowb = r0 + wave*32 + i*16 + quad*4;
#pragma unroll
        for (int reg=0; reg<4; reg++){
            int row = rowb + reg;
            bool valid = row < NNODES;
            float sp=0.f, dp=0.f;
#pragma unroll
            for (int j=0;j<4;j++){
                float v = acc[i][j][reg];
                sp += v*cs[j]; dp += v*cd[j];
                if (valid) h2b[(size_t)row*64 + j*16 + l15] = (short)f2bf(v);
            }
            sp += __shfl_xor(sp,1); sp += __shfl_xor(sp,2); sp += __shfl_xor(sp,4); sp += __shfl_xor(sp,8);
            dp += __shfl_xor(dp,1); dp += __shfl_xor(dp,2); dp += __shfl_xor(dp,4); dp += __shfl_xor(dp,8);
            if (valid && l15 == 0){ as2[row] = sp; ad2[row] = dp; }
        }
    }
}

// ---------------- attention aggregation (single-pass, unroll-4) ------------
// e pre-scaled by log2e -> exp2; leaky = fmax(0.2e, e); packed f32 fma.

__global__ __launch_bounds__(256) void aggregate1_k(const unsigned char* __restrict__ h1f8,
        const float* __restrict__ as1, const float* __restrict__ ad1,
        const int* __restrict__ offsets, const int* __restrict__ deg_g,
        const int* __restrict__ srclist,
        const float* __restrict__ b1, short* __restrict__ out1b){
    int d = blockIdx.x*4 + (threadIdx.x >> 6);
    int lane = threadIdx.x & 63;
    if (d >= NNODES) return;
    int hh = lane >> 3;
    int start = offsets[d];
    int end = start + deg_g[d];
    float ad_h = ad1[d*8 + hh];
    float denom = 0.f;
    f2_t acc01 = {0.f,0.f}, acc23 = {0.f,0.f};
    int k = start;
    for (; k + 3 < end; k += 4){
        int s0 = srclist[k], s1 = srclist[k+1], s2 = srclist[k+2], s3 = srclist[k+3];
        float e0 = as1[s0*8 + hh] + ad_h;
        float e1 = as1[s1*8 + hh] + ad_h;
        float e2 = as1[s2*8 + hh] + ad_h;
        float e3 = as1[s3*8 + hh] + ad_h;
        unsigned w0 = *(const unsigned*)(h1f8 + (size_t)s0*256 + lane*4);
        unsigned w1 = *(const unsigned*)(h1f8 + (size_t)s1*256 + lane*4);
        unsigned w2 = *(const unsigned*)(h1f8 + (size_t)s2*256 + lane*4);
        unsigned w3 = *(const unsigned*)(h1f8 + (size_t)s3*256 + lane*4);
        e0 = fmaxf(0.2f*e0, e0); e1 = fmaxf(0.2f*e1, e1);
        e2 = fmaxf(0.2f*e2, e2); e3 = fmaxf(0.2f*e3, e3);
        float p0 = exp2f(e0), p1 = exp2f(e1), p2 = exp2f(e2), p3 = exp2f(e3);
        denom += (p0 + p1) + (p2 + p3);
        f2_t lo0 = __builtin_amdgcn_cvt_pk_f32_fp8(w0, false), hi0 = __builtin_amdgcn_cvt_pk_f32_fp8(w0, true);
        f2_t lo1 = __builtin_amdgcn_cvt_pk_f32_fp8(w1, false), hi1 = __builtin_amdgcn_cvt_pk_f32_fp8(w1, true);
        f2_t lo2 = __builtin_amdgcn_cvt_pk_f32_fp8(w2, false), hi2 = __builtin_amdgcn_cvt_pk_f32_fp8(w2, true);
        f2_t lo3 = __builtin_amdgcn_cvt_pk_f32_fp8(w3, false), hi3 = __builtin_amdgcn_cvt_pk_f32_fp8(w3, true);
        acc01 += p0*lo0 + p1*lo1 + p2*lo2 + p3*lo3;
        acc23 += p0*hi0 + p1*hi1 + p2*hi2 + p3*hi3;
    }
    for (; k < end; k++){
        int s0 = srclist[k];
        float e0 = as1[s0*8 + hh] + ad_h;
        unsigned w0 = *(const unsigned*)(h1f8 + (size_t)s0*256 + lane*4);
        e0 = fmaxf(0.2f*e0, e0);
        float p0 = exp2f(e0);
        denom += p0;
        f2_t lo0 = __builtin_amdgcn_cvt_pk_f32_fp8(w0, false), hi0 = __builtin_amdgcn_cvt_pk_f32_fp8(w0, true);
        acc01 += p0*lo0;
        acc23 += p0*hi0;
    }
    float inv = 1.f / denom;
    float4 bv = *(const float4*)(b1 + lane*4);
    ushort4 us;
    us.x = f2bf(fmaxf(acc01[0]*inv + bv.x, 0.f));
    us.y = f2bf(fmaxf(acc01[1]*inv + bv.y, 0.f));
    us.z = f2bf(fmaxf(acc23[0]*inv + bv.z, 0.f));
    us.w = f2bf(fmaxf(acc23[1]*inv + bv.w, 0.f));
    *(ushort4*)(out1b + (size_t)d*256 + lane*4) = us;
}

__global__ __launch_bounds__(256) void aggregate2_k(const unsigned short* __restrict__ h2b,
        const float* __restrict__ as2, const float* __restrict__ ad2,
        const int* __restrict__ offsets, const int* __restrict__ deg_g,
        const int* __restrict__ srclist,
        const float* __restrict__ b2, float* __restrict__ out){
    int d = blockIdx.x*4 + (threadIdx.x >> 6);
    int lane = threadIdx.x & 63;
    if (d >= NNODES) return;
    int start = offsets[d];
    int end = start + deg_g[d];
    float ad_v = ad2[d];
    float denom = 0.f, acc = 0.f;
    int k = start;
    for (; k + 3 < end; k += 4){
        int s0 = srclist[k], s1 = srclist[k+1], s2 = srclist[k+2], s3 = srclist[k+3];
        float e0 = as2[s0] + ad_v;
        float e1 = as2[s1] + ad_v;
        float e2 = as2[s2] + ad_v;
        float e3 = as2[s3] + ad_v;
        unsigned short u0 = h2b[(size_t)s0*64 + lane];
        unsigned short u1 = h2b[(size_t)s1*64 + lane];
        unsigned short u2 = h2b[(size_t)s2*64 + lane];
        unsigned short u3 = h2b[(size_t)s3*64 + lane];
        e0 = fmaxf(0.2f*e0, e0); e1 = fmaxf(0.2f*e1, e1);
        e2 = fmaxf(0.2f*e2, e2); e3 = fmaxf(0.2f*e3, e3);
        float p0 = exp2f(e0), p1 = exp2f(e1), p2 = exp2f(e2), p3 = exp2f(e3);
        denom += (p0 + p1) + (p2 + p3);
        acc += p0*bf2f(u0) + p1*bf2f(u1) + p2*bf2f(u2) + p3*bf2f(u3);
    }
    for (; k < end; k++){
        int s0 = srclist[k];
        float e0 = as2[s0] + ad_v;
        unsigned short u0 = h2b[(size_t)s0*64 + lane];
        e0 = fmaxf(0.2f*e0, e0);
        float p0 = exp2f(e0);
        denom += p0;
        acc += p0*bf2f(u0);
    }
    float v = acc/denom + b2[lane];
    float mx = v;
#pragma unroll
    for (int off = 1; off < 64; off <<= 1) mx = fmaxf(mx, __shfl_xor(mx, off));
    float ex = __expf(v - mx);
    float ss = ex;
#pragma unroll
    for (int off = 1; off < 64; off <<= 1) ss += __shfl_xor(ss, off);
    out[(size_t)d*64 + lane] = v - mx - __logf(ss);
}

// ---------------- launch ----------------

extern "C" void kernel_launch(void* const* d_in, const int* in_sizes, int n_in,
                              void* d_out, int out_size, void* d_ws, size_t ws_size,
                              hipStream_t stream){
    const float* x      = (const float*)d_in[0];
    const int*   ei     = (const int*)  d_in[1];
    const float* W1     = (const float*)d_in[2];
    const float* a_src1 = (const float*)d_in[3];
    const float* a_dst1 = (const float*)d_in[4];
    const float* b1     = (const float*)d_in[5];
    const float* W2     = (const float*)d_in[6];
    const float* a_src2 = (const float*)d_in[7];
    const float* a_dst2 = (const float*)d_in[8];
    const float* b2     = (const float*)d_in[9];

    char* ws = (char*)d_ws;
    int*   offsets = (int*)  (ws + OFF_OFFSETS);
    int*   deg_g   = (int*)  (ws + OFF_DEG);
    int*   gcur    = (int*)  (ws + OFF_GCUR);
    int*   epack   = (int*)  (ws + OFF_EPACK);
    int*   srclist = (int*)  (ws + OFF_SRC);
    float* as1     = (float*)(ws + OFF_AS1);
    float* ad1     = (float*)(ws + OFF_AD1);
    short* w1t     = (short*)(ws + OFF_W1T);
    short* w2t     = (short*)(ws + OFF_W2T);
    unsigned char* h1f8 = (unsigned char*)(ws + OFF_H1F8);
    short* out1b   = (short*)(ws + OFF_OUT1B);
    short* h2b     = (short*)(ws + OFF_H2B);
    float* as2     = (float*)(ws + OFF_AS2);
    float* ad2     = (float*)(ws + OFF_AD2);

    // CSR by dst: LDS multisplit with fixed-stride buckets
    ginit  <<<1, 256, 0, stream>>>(gcur);
    p3_part<<<NBLK2, 256, 0, stream>>>(ei, gcur, epack);
    p4_csr <<<NBUCK, 256, 0, stream>>>(gcur, epack, offsets, deg_g, srclist);

    // weight prep (one launch for both layers)
    conv_w_k<<<(256*256 + 64*256 + 255)/256, 256, 0, stream>>>(W1, W2, w1t, w2t);

    // Layer 1
    gemm1_mfma<<<(NNODES+127)/128, 512, 0, stream>>>(x, w1t, a_src1, a_dst1, h1f8, as1, ad1);
    aggregate1_k<<<(NNODES+3)/4, 256, 0, stream>>>(h1f8, as1, ad1, offsets, deg_g, srclist, b1, out1b);

    // Layer 2
    gemm2_mfma<<<(NNODES+127)/128, 256, 0, stream>>>(out1b, w2t, a_src2, a_dst2, h2b, as2, ad2);
    aggregate2_k<<<(NNODES+3)/4, 256, 0, stream>>>((const unsigned short*)h2b, as2, ad2, offsets, deg_g, srclist, b2, (float*)d_out);
}

// Round 9
// 249.445 us; speedup vs baseline: 1.4696x; 1.0522x over previous
//
#include <hip/hip_runtime.h>
#include <math.h>

#define NNODES 50000
#define EORIG  800000
#define ETOT   850000     // EORIG + NNODES self loops
#define NBUCK  196        // ceil(NNODES/256) buckets of 256 nodes (bucket = dst>>8)
#define BSTRIDE 5120      // fixed slots per bucket (mean 4352, +12 sigma headroom)
#define P2CHUNK 4096      // edges per partition block
#define NBLK2  ((ETOT + P2CHUNK - 1)/P2CHUNK)   // 208

typedef __attribute__((ext_vector_type(8))) short bf8_t;   // 8 bf16 (bits in shorts)
typedef __attribute__((ext_vector_type(4))) float f4_t;
typedef __attribute__((ext_vector_type(2))) float f2_t;

constexpr float LOG2E = 1.44269504f;

constexpr size_t align256(size_t x){ return (x + 255) & ~size_t(255); }
constexpr size_t OFF_OFFSETS = 0;                                           // N ints
constexpr size_t OFF_DEG     = OFF_OFFSETS + align256((size_t)NNODES*4);    // N ints
constexpr size_t OFF_GCUR    = OFF_DEG     + align256((size_t)NNODES*4);    // NBUCK ints
constexpr size_t OFF_EPACK   = OFF_GCUR    + align256(NBUCK*4);             // NBUCK*BSTRIDE ints
constexpr size_t OFF_SRC     = OFF_EPACK   + align256((size_t)NBUCK*BSTRIDE*4);
constexpr size_t OFF_AS1     = OFF_SRC     + align256((size_t)NBUCK*BSTRIDE*4); // N*8 f32
constexpr size_t OFF_AD1     = OFF_AS1     + align256((size_t)NNODES*8*4);
constexpr size_t OFF_W1T     = OFF_AD1     + align256((size_t)NNODES*8*4);  // 256*256 bf16 (n-major)
constexpr size_t OFF_W2T     = OFF_W1T     + align256(256*256*2);           // 64*256 bf16 (n-major)
constexpr size_t OFF_H1F8    = OFF_W2T     + align256(64*256*2);            // N*256 fp8
constexpr size_t OFF_OUT1B   = OFF_H1F8    + align256((size_t)NNODES*256);  // N*256 bf16
// h2b overlays dead h1f8 after aggregate1
constexpr size_t OFF_H2B     = OFF_H1F8;                                    // N*64 bf16
constexpr size_t OFF_AS2     = OFF_OUT1B   + align256((size_t)NNODES*256*2);
constexpr size_t OFF_AD2     = OFF_AS2     + align256((size_t)NNODES*4);

__device__ __forceinline__ unsigned short f2bf(float f){
    union { float f; unsigned u; } v; v.f = f;
    unsigned r = v.u + 0x7FFF + ((v.u >> 16) & 1);   // RNE
    return (unsigned short)(r >> 16);
}
__device__ __forceinline__ float bf2f(unsigned short s){
    union { unsigned u; float f; } v; v.u = ((unsigned)s) << 16;
    return v.f;
}

// ---------------- CSR construction: LDS multisplit, fixed-stride buckets ---

// block-level multisplit into fixed-stride bucket regions
// epack = (src<<8) | (dst & 255);  src < 50000 fits in 24 bits.
__global__ __launch_bounds__(256) void p3_part(const int* __restrict__ ei, int* __restrict__ gcur,
                                               int* __restrict__ epack){
    __shared__ int h[NBUCK];    // block hist -> block base per bucket
    __shared__ int r[NBUCK];    // intra-block rank cursor
    const int t = threadIdx.x;
    for (int i = t; i < NBUCK; i += 256){ h[i] = 0; r[i] = 0; }
    __syncthreads();
    const int base = blockIdx.x * P2CHUNK;
    int srcs[P2CHUNK/256], dsts[P2CHUNK/256];
#pragma unroll
    for (int j = 0; j < P2CHUNK/256; j++){
        int e = base + j*256 + t;
        if (e < ETOT){
            if (e < EORIG){ srcs[j] = ei[e]; dsts[j] = ei[EORIG + e]; }
            else          { srcs[j] = dsts[j] = e - EORIG; }
            atomicAdd(&h[dsts[j] >> 8], 1);
        } else dsts[j] = -1;
    }
    __syncthreads();
    for (int i = t; i < NBUCK; i += 256){
        int c = h[i];
        h[i] = c ? atomicAdd(&gcur[i], c) : 0;
    }
    __syncthreads();
#pragma unroll
    for (int j = 0; j < P2CHUNK/256; j++){
        if (dsts[j] >= 0){
            int b = dsts[j] >> 8;
            int rk = atomicAdd(&r[b], 1);
            epack[h[b] + rk] = (srcs[j] << 8) | (dsts[j] & 255);
        }
    }
}

// one block per bucket -> local CSR in LDS; offsets/deg coalesced;
// srclist writes confined to the bucket's contiguous region.
__global__ __launch_bounds__(256) void p4_csr(const int* __restrict__ gcur, const int* __restrict__ epack,
                                              int* __restrict__ offsets, int* __restrict__ deg_g,
                                              int* __restrict__ srclist){
    __shared__ int deg[256];
    __shared__ int sm[256];
    __shared__ int cur[256];
    const int b = blockIdx.x, t = threadIdx.x;
    const int s0 = b * BSTRIDE, s1 = gcur[b];
    deg[t] = 0; __syncthreads();
    for (int i = s0 + t; i < s1; i += 256) atomicAdd(&deg[epack[i] & 255], 1);
    __syncthreads();
    int v = deg[t];
    sm[t] = v; __syncthreads();
    for (int off = 1; off < 256; off <<= 1){
        int add = (t >= off) ? sm[t-off] : 0;
        __syncthreads();
        sm[t] += add;
        __syncthreads();
    }
    int excl = sm[t] - v;
    int node = (b << 8) + t;
    if (node < NNODES){ offsets[node] = s0 + excl; deg_g[node] = v; }
    cur[t] = s0 + excl;
    __syncthreads();
    for (int i = s0 + t; i < s1; i += 256){
        int p = epack[i];
        int pos = atomicAdd(&cur[p & 255], 1);
        srclist[pos] = p >> 8;
    }
}

// ---------------- weight transpose+convert + gcur init (one launch) --------

__global__ __launch_bounds__(256) void conv_w_k(const float* __restrict__ W1, const float* __restrict__ W2,
                                                short* __restrict__ w1t, short* __restrict__ w2t,
                                                int* __restrict__ gcur){
    int o = blockIdx.x*256 + threadIdx.x;
    if (o < NBUCK) gcur[o] = o * BSTRIDE;
    if (o < 256*256){
        int n = o >> 8, k = o & 255;
        w1t[o] = (short)f2bf(W1[k*256 + n]);
    } else {
        int o2 = o - 256*256;
        if (o2 < 64*256){
            int n = o2 >> 8, k = o2 & 255;
            w2t[o2] = (short)f2bf(W2[k*64 + n]);
        }
    }
}

// ---------------- GEMM1 (MFMA): h1f8 = fp8(x @ W1), fused f32->bf16 A-stage
// + fused as1/ad1 epilogue (pre-scaled by log2(e) for exp2-based softmax).
// 128x256 tile, 512 threads = 2x4 waves, BK=32.

__global__ __launch_bounds__(512) void gemm1_mfma(const float* __restrict__ x, const short* __restrict__ w1t,
        const float* __restrict__ a1s, const float* __restrict__ a1d,
        unsigned char* __restrict__ h1f8, float* __restrict__ as1, float* __restrict__ ad1){
    __shared__ short As[128][40];   // +8 pad: 16B-aligned frags, 2-way banks = free
    __shared__ short Bs[256][40];   // Bs[n][k] (from pre-transposed W1T)
    const int t = threadIdx.x;                 // 0..511
    const int lane = t & 63, wave = t >> 6;    // 8 waves
    const int wy = wave >> 2, wx = wave & 3;   // 2 x 4 wave grid
    const int quad = lane >> 4, l15 = lane & 15;
    const int r0 = blockIdx.x * 128;
    const int srow = t >> 2, skoff = (t & 3) * 8;   // srow 0..127
    f4_t zero4 = {0.f,0.f,0.f,0.f};
    f4_t acc[4][4];
#pragma unroll
    for (int i=0;i<4;i++)
#pragma unroll
      for (int j=0;j<4;j++) acc[i][j] = zero4;

    for (int kk = 0; kk < 256; kk += 32){
        float4 xa0 = {0,0,0,0}, xa1 = {0,0,0,0};
        if (r0 + srow < NNODES){
            xa0 = *(const float4*)(x + (size_t)(r0+srow)*256 + kk + skoff);
            xa1 = *(const float4*)(x + (size_t)(r0+srow)*256 + kk + skoff + 4);
        }
        bf8_t b0  = *(const bf8_t*)(w1t + (size_t)(srow      )*256 + kk + skoff);
        bf8_t b1v = *(const bf8_t*)(w1t + (size_t)(srow + 128)*256 + kk + skoff);
        bf8_t a0;
        a0[0]=f2bf(xa0.x); a0[1]=f2bf(xa0.y); a0[2]=f2bf(xa0.z); a0[3]=f2bf(xa0.w);
        a0[4]=f2bf(xa1.x); a0[5]=f2bf(xa1.y); a0[6]=f2bf(xa1.z); a0[7]=f2bf(xa1.w);
        __syncthreads();
        *(bf8_t*)&As[srow     ][skoff] = a0;
        *(bf8_t*)&Bs[srow     ][skoff] = b0;
        *(bf8_t*)&Bs[srow+128][skoff] = b1v;
        __syncthreads();
        bf8_t af[4], bfr[4];
#pragma unroll
        for (int i=0;i<4;i++) af[i]  = *(const bf8_t*)&As[wy*64 + i*16 + l15][quad*8];
#pragma unroll
        for (int j=0;j<4;j++) bfr[j] = *(const bf8_t*)&Bs[wx*64 + j*16 + l15][quad*8];
#pragma unroll
        for (int i=0;i<4;i++)
#pragma unroll
          for (int j=0;j<4;j++)
            acc[i][j] = __builtin_amdgcn_mfma_f32_16x16x32_bf16(af[i], bfr[j], acc[i][j], 0,0,0);
    }
    // epilogue: fp8 store (HW cvt) + fused alpha projections (x log2e)
    const int colbase = wx*64;               // this wave's 64 cols = 2 heads
    const int head0 = colbase >> 5;
    float cs[4], cd[4];
#pragma unroll
    for (int j=0;j<4;j++){
        cs[j] = a1s[colbase + j*16 + l15] * LOG2E;
        cd[j] = a1d[colbase + j*16 + l15] * LOG2E;
    }
#pragma unroll
    for (int i=0;i<4;i++){
        int rowb = r0 + wy*64 + i*16 + quad*4;
#pragma unroll
        for (int reg=0; reg<4; reg++){
            int row = rowb + reg;
            bool valid = row < NNODES;
            float sp0=0.f, dp0=0.f, sp1=0.f, dp1=0.f;
#pragma unroll
            for (int j=0;j<4;j++){
                float v = acc[i][j][reg];
                if (j < 2){ sp0 += v*cs[j]; dp0 += v*cd[j]; }
                else      { sp1 += v*cs[j]; dp1 += v*cd[j]; }
                if (valid){
                    unsigned enc = (unsigned)__builtin_amdgcn_cvt_pk_fp8_f32(v, v, 0, false);
                    h1f8[(size_t)row*256 + colbase + j*16 + l15] = (unsigned char)(enc & 0xffu);
                }
            }
            sp0 += __shfl_xor(sp0,1); sp0 += __shfl_xor(sp0,2); sp0 += __shfl_xor(sp0,4); sp0 += __shfl_xor(sp0,8);
            dp0 += __shfl_xor(dp0,1); dp0 += __shfl_xor(dp0,2); dp0 += __shfl_xor(dp0,4); dp0 += __shfl_xor(dp0,8);
            sp1 += __shfl_xor(sp1,1); sp1 += __shfl_xor(sp1,2); sp1 += __shfl_xor(sp1,4); sp1 += __shfl_xor(sp1,8);
            dp1 += __shfl_xor(dp1,1); dp1 += __shfl_xor(dp1,2); dp1 += __shfl_xor(dp1,4); dp1 += __shfl_xor(dp1,8);
            if (valid && l15 == 0){
                as1[row*8 + head0    ] = sp0;
                ad1[row*8 + head0    ] = dp0;
                as1[row*8 + head0 + 1] = sp1;
                ad1[row*8 + head0 + 1] = dp1;
            }
        }
    }
}

// ---------------- GEMM2 (MFMA): h2b = bf16(out1b @ W2), fused as2/ad2 ------

__global__ __launch_bounds__(256) void gemm2_mfma(const short* __restrict__ ab, const short* __restrict__ w2t,
        const float* __restrict__ a2s, const float* __restrict__ a2d,
        short* __restrict__ h2b, float* __restrict__ as2, float* __restrict__ ad2){
    __shared__ short As[128][40];
    __shared__ short Bs[64][40];
    const int t = threadIdx.x;
    const int lane = t & 63, wave = t >> 6;
    const int quad = lane >> 4, l15 = lane & 15;
    const int r0 = blockIdx.x * 128;
    const int srow = t >> 2, skoff = (t & 3) * 8;
    f4_t zero4 = {0.f,0.f,0.f,0.f};
    f4_t acc[2][4];
#pragma unroll
    for (int i=0;i<2;i++)
#pragma unroll
      for (int j=0;j<4;j++) acc[i][j] = zero4;

    for (int kk = 0; kk < 256; kk += 32){
        bf8_t a0 = {}, a1v = {};
        if (r0 + srow < NNODES)      a0  = *(const bf8_t*)(ab + (size_t)(r0+srow)*256 + kk + skoff);
        if (r0 + srow + 64 < NNODES) a1v = *(const bf8_t*)(ab + (size_t)(r0+srow+64)*256 + kk + skoff);
        bf8_t b0 = *(const bf8_t*)(w2t + (size_t)srow*256 + kk + skoff);   // srow = n (0..63)
        __syncthreads();
        *(bf8_t*)&As[srow   ][skoff] = a0;
        *(bf8_t*)&As[srow+64][skoff] = a1v;
        *(bf8_t*)&Bs[srow   ][skoff] = b0;
        __syncthreads();
        bf8_t af[2], bfr[4];
#pragma unroll
        for (int i=0;i<2;i++) af[i]  = *(const bf8_t*)&As[wave*32 + i*16 + l15][quad*8];
#pragma unroll
        for (int j=0;j<4;j++) bfr[j] = *(const bf8_t*)&Bs[j*16 + l15][quad*8];
#pragma unroll
        for (int i=0;i<2;i++)
#pragma unroll
          for (int j=0;j<4;j++)
            acc[i][j] = __builtin_amdgcn_mfma_f32_16x16x32_bf16(af[i], bfr[j], acc[i][j], 0,0,0);
    }
    float cs[4], cd[4];
#pragma unroll
    for (int j=0;j<4;j++){
        cs[j] = a2s[j*16 + l15] * LOG2E;
        cd[j] = a2d[j*16 + l15] * LOG2E;
    }
#pragma unroll
    for (int i=0;i<2;i++){
        int rowb = r0 + wave*32 + i*16 + quad*4;
#pragma unroll
        for (int reg=0; reg<4; reg++){
            int row = rowb + reg;
            bool valid = row < NNODES;
            float sp=0.f, dp=0.f;
#pragma unroll
            for (int j=0;j<4;j++){
                float v = acc[i][j][reg];
                sp += v*cs[j]; dp += v*cd[j];
                if (valid) h2b[(size_t)row*64 + j*16 + l15] = (short)f2bf(v);
            }
            sp += __shfl_xor(sp,1); sp += __shfl_xor(sp,2); sp += __shfl_xor(sp,4); sp += __shfl_xor(sp,8);
            dp += __shfl_xor(dp,1); dp += __shfl_xor(dp,2); dp += __shfl_xor(dp,4); dp += __shfl_xor(dp,8);
            if (valid && l15 == 0){ as2[row] = sp; ad2[row] = dp; }
        }
    }
}

// ---------------- attention aggregation, restructured -----------------------
// Lane-indexed srclist preload; dedup'd p computation (1 exp per 8 edges);
// software-pipelined p vs gather; 8 gathers in flight per group.

__global__ __launch_bounds__(256) void aggregate1_k(const unsigned char* __restrict__ h1f8,
        const float* __restrict__ as1, const float* __restrict__ ad1,
        const int* __restrict__ offsets, const int* __restrict__ deg_g,
        const int* __restrict__ srclist,
        const float* __restrict__ b1, short* __restrict__ out1b){
    int d = blockIdx.x*4 + (threadIdx.x >> 6);
    int lane = threadIdx.x & 63;
    if (d >= NNODES) return;
    const int head_g = lane >> 3;    // gather phase: lane covers channels head_g*32 + (lane&7)*4 ..
    const int head_p = lane & 7;     // p phase: lane computes p(edge = lane>>3, head = lane&7)
    const int ep     = lane >> 3;
    int start = offsets[d];
    int deg = deg_g[d];
    float ad_p = ad1[d*8 + head_p];
    float denom = 0.f;
    f2_t acc01 = {0.f,0.f}, acc23 = {0.f,0.f};
    for (int w = 0; w < deg; w += 64){
        int deg_w = min(64, deg - w);
        int s_reg = srclist[start + w + min(lane, deg_w-1)];
        int ngr = (deg_w + 7) >> 3;
        // p for group g: edges g*8 .. g*8+7 of this window, all 8 heads
        auto comp_p = [&](int g)->float{
            int ei = g*8 + ep;
            int s  = __shfl(s_reg, min(ei, deg_w-1));
            float e = as1[s*8 + head_p] + ad_p;
            e = fmaxf(0.2f*e, e);
            float p = exp2f(e);
            return (ei < deg_w) ? p : 0.f;
        };
        float p_reg = comp_p(0);
        for (int g = 0; g < ngr; g++){
            float p_cur = p_reg;
            if (g + 1 < ngr) p_reg = comp_p(g+1);
#pragma unroll
            for (int e = 0; e < 8; e++){
                float pe = __shfl(p_cur, e*8 + head_g);
                int   se = __shfl(s_reg, g*8 + e);
                unsigned wv = *(const unsigned*)(h1f8 + (size_t)se*256 + lane*4);
                f2_t lo = __builtin_amdgcn_cvt_pk_f32_fp8(wv, false);
                f2_t hi = __builtin_amdgcn_cvt_pk_f32_fp8(wv, true);
                acc01 += pe*lo;
                acc23 += pe*hi;
                denom += pe;
            }
        }
    }
    float inv = 1.f / denom;
    float4 bv = *(const float4*)(b1 + lane*4);
    ushort4 us;
    us.x = f2bf(fmaxf(acc01[0]*inv + bv.x, 0.f));
    us.y = f2bf(fmaxf(acc01[1]*inv + bv.y, 0.f));
    us.z = f2bf(fmaxf(acc23[0]*inv + bv.z, 0.f));
    us.w = f2bf(fmaxf(acc23[1]*inv + bv.w, 0.f));
    *(ushort4*)(out1b + (size_t)d*256 + lane*4) = us;
}

__global__ __launch_bounds__(256) void aggregate2_k(const unsigned short* __restrict__ h2b,
        const float* __restrict__ as2, const float* __restrict__ ad2,
        const int* __restrict__ offsets, const int* __restrict__ deg_g,
        const int* __restrict__ srclist,
        const float* __restrict__ b2, float* __restrict__ out){
    int d = blockIdx.x*4 + (threadIdx.x >> 6);
    int lane = threadIdx.x & 63;
    if (d >= NNODES) return;
    int start = offsets[d];
    int deg = deg_g[d];
    float ad_v = ad2[d];
    float denom = 0.f, acc = 0.f;
    for (int w = 0; w < deg; w += 64){
        int deg_w = min(64, deg - w);
        int s_reg = srclist[start + w + min(lane, deg_w-1)];
        float ev = as2[s_reg] + ad_v;
        ev = fmaxf(0.2f*ev, ev);
        float p_lane = (lane < deg_w) ? exp2f(ev) : 0.f;
        int ngr = (deg_w + 7) >> 3;
        for (int g = 0; g < ngr; g++){
#pragma unroll
            for (int e2 = 0; e2 < 8; e2++){
                int ee = g*8 + e2;
                float pe = __shfl(p_lane, ee);
                int   se = __shfl(s_reg, ee);
                float hv = bf2f(h2b[(size_t)se*64 + lane]);
                acc += pe*hv;
                denom += pe;
            }
        }
    }
    float v = acc/denom + b2[lane];
    float mx = v;
#pragma unroll
    for (int off = 1; off < 64; off <<= 1) mx = fmaxf(mx, __shfl_xor(mx, off));
    float ex = __expf(v - mx);
    float ss = ex;
#pragma unroll
    for (int off = 1; off < 64; off <<= 1) ss += __shfl_xor(ss, off);
    out[(size_t)d*64 + lane] = v - mx - __logf(ss);
}

// ---------------- launch ----------------

extern "C" void kernel_launch(void* const* d_in, const int* in_sizes, int n_in,
                              void* d_out, int out_size, void* d_ws, size_t ws_size,
                              hipStream_t stream){
    const float* x      = (const float*)d_in[0];
    const int*   ei     = (const int*)  d_in[1];
    const float* W1     = (const float*)d_in[2];
    const float* a_src1 = (const float*)d_in[3];
    const float* a_dst1 = (const float*)d_in[4];
    const float* b1     = (const float*)d_in[5];
    const float* W2     = (const float*)d_in[6];
    const float* a_src2 = (const float*)d_in[7];
    const float* a_dst2 = (const float*)d_in[8];
    const float* b2     = (const float*)d_in[9];

    char* ws = (char*)d_ws;
    int*   offsets = (int*)  (ws + OFF_OFFSETS);
    int*   deg_g   = (int*)  (ws + OFF_DEG);
    int*   gcur    = (int*)  (ws + OFF_GCUR);
    int*   epack   = (int*)  (ws + OFF_EPACK);
    int*   srclist = (int*)  (ws + OFF_SRC);
    float* as1     = (float*)(ws + OFF_AS1);
    float* ad1     = (float*)(ws + OFF_AD1);
    short* w1t     = (short*)(ws + OFF_W1T);
    short* w2t     = (short*)(ws + OFF_W2T);
    unsigned char* h1f8 = (unsigned char*)(ws + OFF_H1F8);
    short* out1b   = (short*)(ws + OFF_OUT1B);
    short* h2b     = (short*)(ws + OFF_H2B);
    float* as2     = (float*)(ws + OFF_AS2);
    float* ad2     = (float*)(ws + OFF_AD2);

    // weight prep + gcur init (must precede p3)
    conv_w_k<<<(256*256 + 64*256 + 255)/256, 256, 0, stream>>>(W1, W2, w1t, w2t, gcur);

    // CSR by dst: LDS multisplit with fixed-stride buckets
    p3_part<<<NBLK2, 256, 0, stream>>>(ei, gcur, epack);
    p4_csr <<<NBUCK, 256, 0, stream>>>(gcur, epack, offsets, deg_g, srclist);

    // Layer 1
    gemm1_mfma<<<(NNODES+127)/128, 512, 0, stream>>>(x, w1t, a_src1, a_dst1, h1f8, as1, ad1);
    aggregate1_k<<<(NNODES+3)/4, 256, 0, stream>>>(h1f8, as1, ad1, offsets, deg_g, srclist, b1, out1b);

    // Layer 2
    gemm2_mfma<<<(NNODES+127)/128, 256, 0, stream>>>(out1b, w2t, a_src2, a_dst2, h2b, as2, ad2);
    aggregate2_k<<<(NNODES+3)/4, 256, 0, stream>>>((const unsigned short*)h2b, as2, ad2, offsets, deg_g, srclist, b2, (float*)d_out);
}